// Round 4
// baseline (3107.495 us; speedup 1.0000x reference)
//
#include <hip/hip_runtime.h>
#include <hip/hip_bf16.h>
#include <math.h>

#define N_NODES  200000
#define NNZ_CNT  3200000
#define N_GRAPHS 256
#define N2R      400000              // 2*N_NODES concatenated rows (up then down)
#define BSHIFT   9
#define BROWS    512                 // rows per bucket
#define NB       ((N2R + BROWS - 1) / BROWS)   // 782 buckets

// ============ CSR build via bucketed counting sort ============
// k1: bucket histogram (LDS-aggregated). 391 blocks x 16384 entries.
__global__ __launch_bounds__(256) void bucket_count_k(const int* __restrict__ rows0,
                                                      const int* __restrict__ rows1,
                                                      int* __restrict__ bcnt) {
  __shared__ int h[NB];
  int t = threadIdx.x;
  for (int i = t; i < NB; i += 256) h[i] = 0;
  __syncthreads();
  long long base = (long long)blockIdx.x * 16384;
  long long lim = base + 16384; if (lim > 2LL * NNZ_CNT) lim = 2LL * NNZ_CNT;
  for (long long e = base + t; e < lim; e += 256) {
    int r = (e < NNZ_CNT) ? rows0[e] : (rows1[e - NNZ_CNT] + N_NODES);
    atomicAdd(&h[r >> BSHIFT], 1);
  }
  __syncthreads();
  for (int i = t; i < NB; i += 256) if (h[i]) atomicAdd(&bcnt[i], h[i]);
}

// k2: scan 782 bucket counts (one wave), init bofs + bnxt, set rp2[N2R]
__global__ void bucket_scan_k(const int* __restrict__ bcnt, int* __restrict__ bofs,
                              int* __restrict__ bnxt, int* __restrict__ rp2) {
  int t = threadIdx.x;   // 64 threads
  int run = 0;
  for (int base = 0; base < NB; base += 64) {
    int idx = base + t;
    int v = (idx < NB) ? bcnt[idx] : 0;
    int x = v;
    #pragma unroll
    for (int d = 1; d < 64; d <<= 1) { int y = __shfl_up(x, d); if (t >= d) x += y; }
    int excl = run + x - v;
    if (idx < NB) { bofs[idx] = excl; bnxt[idx] = excl; }
    run += __shfl(x, 63);
  }
  if (t == 0) { bofs[NB] = run; rp2[N2R] = run; }
}

// k3: scatter entries into bucket regions (packed 8B; tail-dense writes)
__global__ __launch_bounds__(256) void bucket_scatter_k(
    const int* __restrict__ rows0, const int* __restrict__ cols0, const float* __restrict__ vals0,
    const int* __restrict__ rows1, const int* __restrict__ cols1, const float* __restrict__ vals1,
    int* __restrict__ bnxt, int2* __restrict__ tmp) {
  int i = blockIdx.x * 256 + threadIdx.x;
  int r, c; float v;
  if (i < NNZ_CNT) {
    r = rows0[i]; c = cols0[i]; v = vals0[i];
  } else if (i < 2 * NNZ_CNT) {
    int k = i - NNZ_CNT;
    r = rows1[k] + N_NODES; c = cols1[k]; v = vals1[k];
  } else return;
  int p = atomicAdd(&bnxt[r >> BSHIFT], 1);
  tmp[p] = make_int2(c | ((r & (BROWS - 1)) << 18), __float_as_int(v));
}

// k4: per-bucket CSR finalize — LDS row histogram + scan, coalesced rp2 write,
// then place entries via LDS atomics into the bucket's L2-resident CSR range.
__global__ __launch_bounds__(256) void bucket_build_k(const int2* __restrict__ tmp,
    const int* __restrict__ bofs, int* __restrict__ rp2, int2* __restrict__ cv) {
  __shared__ int hist[BROWS];
  __shared__ int lpos[BROWS];
  int b = blockIdx.x;
  int t = threadIdx.x;
  int beg = bofs[b], end = bofs[b + 1];
  for (int i = t; i < BROWS; i += 256) hist[i] = 0;
  __syncthreads();
  for (int e = beg + t; e < end; e += 256)
    atomicAdd(&hist[(tmp[e].x >> 18) & (BROWS - 1)], 1);
  __syncthreads();
  if (t < 64) {
    int run = beg;
    for (int base = 0; base < BROWS; base += 64) {
      int v = hist[base + t];
      int x = v;
      #pragma unroll
      for (int d = 1; d < 64; d <<= 1) { int y = __shfl_up(x, d); if (t >= d) x += y; }
      lpos[base + t] = run + x - v;
      run += __shfl(x, 63);
    }
  }
  __syncthreads();
  int r0 = b << BSHIFT;
  for (int i = t; i < BROWS; i += 256)
    if (r0 + i < N2R) rp2[r0 + i] = lpos[i];
  __syncthreads();   // rp2 reads of lpos must complete before atomics mutate it
  for (int e = beg + t; e < end; e += 256) {
    int2 ent = tmp[e];
    int rl = (ent.x >> 18) & (BROWS - 1);
    int p = atomicAdd(&lpos[rl], 1);
    cv[p] = make_int2(ent.x & 0x3FFFF, ent.y);
  }
}

// ============ layer-1 GEMM: [N,128] @ [128,32] (heads concat) ============
__global__ __launch_bounds__(256) void gemm1_k(const float* __restrict__ X, const float* __restrict__ W,
                                               float* __restrict__ H, int n) {
  __shared__ float Ws[128 * 32];
  __shared__ float Xs[128 * 33];
  int t = threadIdx.x;
  for (int idx = t; idx < 4096; idx += 256) {
    int hh = idx >> 11, rem = idx & 2047, k = rem >> 4, f = rem & 15;
    Ws[k * 32 + hh * 16 + f] = W[idx];
  }
  int r0 = blockIdx.x * 128;
  int rt = t >> 3, ct = t & 7;
  float acc[4][4];
  #pragma unroll
  for (int i = 0; i < 4; ++i)
    #pragma unroll
    for (int j = 0; j < 4; ++j) acc[i][j] = 0.f;
  for (int k0 = 0; k0 < 128; k0 += 32) {
    __syncthreads();
    #pragma unroll
    for (int pp = 0; pp < 4; ++pp) {
      int f4 = pp * 256 + t;
      int row = f4 >> 3, q = f4 & 7;
      int rr = r0 + row;
      float4 v = make_float4(0.f, 0.f, 0.f, 0.f);
      if (rr < n) v = *(const float4*)&X[rr * 128 + k0 + q * 4];
      Xs[row * 33 + q * 4 + 0] = v.x;
      Xs[row * 33 + q * 4 + 1] = v.y;
      Xs[row * 33 + q * 4 + 2] = v.z;
      Xs[row * 33 + q * 4 + 3] = v.w;
    }
    __syncthreads();
    #pragma unroll
    for (int kk = 0; kk < 32; ++kk) {
      int k = k0 + kk;
      float4 wv = *(const float4*)&Ws[k * 32 + ct * 4];
      float xv[4];
      #pragma unroll
      for (int i = 0; i < 4; ++i) xv[i] = Xs[(rt * 4 + i) * 33 + kk];
      #pragma unroll
      for (int i = 0; i < 4; ++i) {
        acc[i][0] += xv[i] * wv.x;
        acc[i][1] += xv[i] * wv.y;
        acc[i][2] += xv[i] * wv.z;
        acc[i][3] += xv[i] * wv.w;
      }
    }
  }
  #pragma unroll
  for (int i = 0; i < 4; ++i) {
    int rr = r0 + rt * 4 + i;
    if (rr < n)
      *(float4*)&H[rr * 32 + ct * 4] = make_float4(acc[i][0], acc[i][1], acc[i][2], acc[i][3]);
  }
}

// ============ per-row attention scores s1,s2 for layer 1 ============
__global__ void s_l1_k(const float* __restrict__ H, const float* __restrict__ a1,
                       const float* __restrict__ a2, float* __restrict__ s, int n) {
  int i = blockIdx.x * 256 + threadIdx.x;
  if (i >= n) return;
  const float* h = H + (size_t)i * 32;
  float s1u = 0.f, s2u = 0.f, s1d = 0.f, s2d = 0.f;
  #pragma unroll
  for (int f = 0; f < 16; ++f) {
    float au = fabsf(h[f]);
    s1u += au * a1[f]; s2u += au * a2[f];
    float ad = fabsf(h[16 + f]);
    s1d += ad * a1[16 + f]; s2d += ad * a2[16 + f];
  }
  s[i] = s1u; s[n + i] = s2u; s[2 * n + i] = s1d; s[3 * n + i] = s2d;
}

// ============ fused softmax+SpMM, f_out=16, both heads in one launch ============
__global__ __launch_bounds__(256) void spmm16_dual_k(
    const int* __restrict__ rp2, const int2* __restrict__ cv,
    const float* __restrict__ H, const float* __restrict__ s, float* __restrict__ out, int n) {
  int wid2 = (blockIdx.x * 256 + threadIdx.x) >> 6;
  if (wid2 >= 2 * n) return;
  int lane = threadIdx.x & 63;
  int h = (wid2 >= n) ? 1 : 0;
  int wid = wid2 - h * n;
  const float* s1 = s + (size_t)(2 * h) * n;
  const float* s2 = s + (size_t)(2 * h + 1) * n;
  int ho = h * 16;
  int beg = rp2[wid2], end = rp2[wid2 + 1];
  int cnt = end - beg;
  float s1r = s1[wid];
  float4 acc = make_float4(0.f, 0.f, 0.f, 0.f);
  int j = lane >> 2, f = lane & 3;
  if (cnt <= 64) {
    int cl = 0; float vl = 0.f, sc = -1e30f;
    if (lane < cnt) {
      int2 e = cv[beg + lane];
      cl = e.x; vl = __int_as_float(e.y);
      sc = s1r + s2[cl];
    }
    float m = sc;
    #pragma unroll
    for (int d = 32; d; d >>= 1) m = fmaxf(m, __shfl_xor(m, d));
    float el = (lane < cnt) ? __expf(sc - m) : 0.f;
    float es = el;
    #pragma unroll
    for (int d = 32; d; d >>= 1) es += __shfl_xor(es, d);
    float att = (cnt > 0) ? el * vl / es : 0.f;
    for (int t = 0; t < cnt; t += 16) {
      int e = t + j;
      float a = __shfl(att, e);
      int   c = __shfl(cl, e);
      if (e < cnt) {
        const float4 hv = *(const float4*)&H[(size_t)c * 32 + ho + f * 4];
        acc.x += a * hv.x; acc.y += a * hv.y; acc.z += a * hv.z; acc.w += a * hv.w;
      }
    }
  } else {
    float vmax = -1e30f;
    for (int e = beg + lane; e < end; e += 64) vmax = fmaxf(vmax, s1r + s2[cv[e].x]);
    #pragma unroll
    for (int d = 32; d; d >>= 1) vmax = fmaxf(vmax, __shfl_xor(vmax, d));
    float esum = 0.f;
    for (int e = beg + lane; e < end; e += 64) esum += __expf(s1r + s2[cv[e].x] - vmax);
    #pragma unroll
    for (int d = 32; d; d >>= 1) esum += __shfl_xor(esum, d);
    float inv = 1.f / esum;
    for (int t = 0; t < cnt; t += 16) {
      int e = t + j;
      if (e < cnt) {
        int2 ecv = cv[beg + e];
        int c = ecv.x;
        float a = __expf(s1r + s2[c] - vmax) * inv * __int_as_float(ecv.y);
        const float4 hv = *(const float4*)&H[(size_t)c * 32 + ho + f * 4];
        acc.x += a * hv.x; acc.y += a * hv.y; acc.z += a * hv.z; acc.w += a * hv.w;
      }
    }
  }
  #pragma unroll
  for (int d = 4; d < 64; d <<= 1) {
    acc.x += __shfl_xor(acc.x, d);
    acc.y += __shfl_xor(acc.y, d);
    acc.z += __shfl_xor(acc.z, d);
    acc.w += __shfl_xor(acc.w, d);
  }
  if (lane < 4)
    *(float4*)&out[(size_t)wid * 32 + ho + lane * 4] =
      make_float4(fmaxf(acc.x, 0.f), fmaxf(acc.y, 0.f), fmaxf(acc.z, 0.f), fmaxf(acc.w, 0.f));
}

// ============ fused softmax+SpMM, f_out=64 ============
template <int MODE>
__global__ __launch_bounds__(256) void spmm64_k(const int* __restrict__ rp, const int2* __restrict__ cv,
    const float* __restrict__ H, const float* __restrict__ s1,
    const float* __restrict__ s2, float* __restrict__ out, int n) {
  int wid = (blockIdx.x * 256 + threadIdx.x) >> 6;
  if (wid >= n) return;
  int lane = threadIdx.x & 63;
  int beg = rp[wid], end = rp[wid + 1];
  int cnt = end - beg;
  float s1r = s1[wid];
  float4 acc = make_float4(0.f, 0.f, 0.f, 0.f);
  int j = lane >> 4, f = lane & 15;
  if (cnt <= 64) {
    int cl = 0; float vl = 0.f, sc = -1e30f;
    if (lane < cnt) {
      int2 e = cv[beg + lane];
      cl = e.x; vl = __int_as_float(e.y);
      sc = s1r + s2[cl];
    }
    float m = sc;
    #pragma unroll
    for (int d = 32; d; d >>= 1) m = fmaxf(m, __shfl_xor(m, d));
    float el = (lane < cnt) ? __expf(sc - m) : 0.f;
    float es = el;
    #pragma unroll
    for (int d = 32; d; d >>= 1) es += __shfl_xor(es, d);
    float att = (cnt > 0) ? el * vl / es : 0.f;
    for (int t = 0; t < cnt; t += 4) {
      int e = t + j;
      float a = __shfl(att, e);
      int   c = __shfl(cl, e);
      if (e < cnt) {
        const float4 hv = *(const float4*)&H[(size_t)c * 64 + f * 4];
        acc.x += a * hv.x; acc.y += a * hv.y; acc.z += a * hv.z; acc.w += a * hv.w;
      }
    }
  } else {
    float vmax = -1e30f;
    for (int e = beg + lane; e < end; e += 64) vmax = fmaxf(vmax, s1r + s2[cv[e].x]);
    #pragma unroll
    for (int d = 32; d; d >>= 1) vmax = fmaxf(vmax, __shfl_xor(vmax, d));
    float esum = 0.f;
    for (int e = beg + lane; e < end; e += 64) esum += __expf(s1r + s2[cv[e].x] - vmax);
    #pragma unroll
    for (int d = 32; d; d >>= 1) esum += __shfl_xor(esum, d);
    float inv = 1.f / esum;
    for (int t = 0; t < cnt; t += 4) {
      int e = t + j;
      if (e < cnt) {
        int2 ecv = cv[beg + e];
        int c = ecv.x;
        float a = __expf(s1r + s2[c] - vmax) * inv * __int_as_float(ecv.y);
        const float4 hv = *(const float4*)&H[(size_t)c * 64 + f * 4];
        acc.x += a * hv.x; acc.y += a * hv.y; acc.z += a * hv.z; acc.w += a * hv.w;
      }
    }
  }
  #pragma unroll
  for (int d = 16; d < 64; d <<= 1) {
    acc.x += __shfl_xor(acc.x, d);
    acc.y += __shfl_xor(acc.y, d);
    acc.z += __shfl_xor(acc.z, d);
    acc.w += __shfl_xor(acc.w, d);
  }
  if (lane < 16) {
    size_t o = (size_t)wid * 64 + lane * 4;
    if (MODE == 0) {
      *(float4*)&out[o] = acc;
    } else {
      float4 prev = *(const float4*)&out[o];
      *(float4*)&out[o] = make_float4(fmaxf(prev.x + acc.x, 0.f), fmaxf(prev.y + acc.y, 0.f),
                                      fmaxf(prev.z + acc.z, 0.f), fmaxf(prev.w + acc.w, 0.f));
    }
  }
}

// ============ layer-2 GEMM [N,32]@[32,32] + fused s1/s2 ============
__global__ __launch_bounds__(256) void gemm2_k(const float* __restrict__ X, const float* __restrict__ W,
    const float* __restrict__ a1, const float* __restrict__ a2, float* __restrict__ H,
    float* __restrict__ s, int n) {
  __shared__ float Ws[32 * 32];
  int t = threadIdx.x;
  for (int idx = t; idx < 1024; idx += 256) {
    int hh = idx >> 9, rem = idx & 511, k = rem >> 4, f = rem & 15;
    Ws[k * 32 + hh * 16 + f] = W[idx];
  }
  __syncthreads();
  int i = blockIdx.x * 256 + t;
  if (i >= n) return;
  float x[32];
  const float4* xp = (const float4*)(X + (size_t)i * 32);
  #pragma unroll
  for (int q = 0; q < 8; ++q) { float4 v = xp[q]; x[q*4] = v.x; x[q*4+1] = v.y; x[q*4+2] = v.z; x[q*4+3] = v.w; }
  float acc[32];
  #pragma unroll
  for (int c = 0; c < 32; ++c) acc[c] = 0.f;
  #pragma unroll 8
  for (int k = 0; k < 32; ++k) {
    float xk = x[k];
    #pragma unroll
    for (int c = 0; c < 32; ++c) acc[c] += xk * Ws[k * 32 + c];
  }
  float s1u = 0.f, s2u = 0.f, s1d = 0.f, s2d = 0.f;
  #pragma unroll
  for (int f = 0; f < 16; ++f) {
    float au = fabsf(acc[f]);      s1u += au * a1[f];      s2u += au * a2[f];
    float ad = fabsf(acc[16 + f]); s1d += ad * a1[16 + f]; s2d += ad * a2[16 + f];
  }
  float4* hp = (float4*)(H + (size_t)i * 32);
  #pragma unroll
  for (int q = 0; q < 8; ++q) hp[q] = make_float4(acc[q*4], acc[q*4+1], acc[q*4+2], acc[q*4+3]);
  s[i] = s1u; s[n + i] = s2u; s[2 * n + i] = s1d; s[3 * n + i] = s2d;
}

// ============ layer-4 GEMM [N,32]@[32,64] per head + fused s1/s2 ============
__global__ __launch_bounds__(256) void gemm4_k(const float* __restrict__ X, const float* __restrict__ W,
    const float* __restrict__ a1, const float* __restrict__ a2, float* __restrict__ H,
    float* __restrict__ s1o, float* __restrict__ s2o, int n) {
  __shared__ float Ws[32 * 64];
  int t = threadIdx.x;
  for (int idx = t; idx < 2048; idx += 256) Ws[idx] = W[idx];
  __syncthreads();
  int i = blockIdx.x * 256 + t;
  if (i >= n) return;
  float x[32];
  const float4* xp = (const float4*)(X + (size_t)i * 32);
  #pragma unroll
  for (int q = 0; q < 8; ++q) { float4 v = xp[q]; x[q*4] = v.x; x[q*4+1] = v.y; x[q*4+2] = v.z; x[q*4+3] = v.w; }
  float acc[64];
  #pragma unroll
  for (int c = 0; c < 64; ++c) acc[c] = 0.f;
  for (int k = 0; k < 32; ++k) {
    float xk = x[k];
    #pragma unroll
    for (int c = 0; c < 64; ++c) acc[c] += xk * Ws[k * 64 + c];
  }
  float s1v = 0.f, s2v = 0.f;
  #pragma unroll
  for (int c = 0; c < 64; ++c) { float a = fabsf(acc[c]); s1v += a * a1[c]; s2v += a * a2[c]; }
  float4* hp = (float4*)(H + (size_t)i * 64);
  #pragma unroll
  for (int q = 0; q < 16; ++q) hp[q] = make_float4(acc[q*4], acc[q*4+1], acc[q*4+2], acc[q*4+3]);
  s1o[i] = s1v; s2o[i] = s2v;
}

// ============ pooling ============
__global__ void graph_bounds_k(const int* __restrict__ batch, int n, int* __restrict__ off) {
  int g = blockIdx.x * 256 + threadIdx.x;
  if (g > N_GRAPHS) return;
  int lo = 0, hi = n;
  while (lo < hi) { int mid = (lo + hi) >> 1; if (batch[mid] < g) lo = mid + 1; else hi = mid; }
  off[g] = lo;
}

__global__ __launch_bounds__(256) void pool_k(const float* __restrict__ X, const int* __restrict__ off,
                                              float* __restrict__ out) {
  __shared__ float sm[256];
  int g = blockIdx.x;
  int beg = off[g], end = off[g + 1];
  int t = threadIdx.x;
  int f = t & 63, j = t >> 6;
  float acc = 0.f;
  for (int r = beg + j; r < end; r += 4) acc += X[(size_t)r * 64 + f];
  sm[t] = acc;
  __syncthreads();
  if (j == 0) {
    float ssum = sm[f] + sm[64 + f] + sm[128 + f] + sm[192 + f];
    float cnt = (float)(end - beg);
    float p = ssum / fmaxf(cnt, 1.f);
    float m = p;
    #pragma unroll
    for (int d = 32; d; d >>= 1) m = fmaxf(m, __shfl_xor(m, d));
    float e = __expf(p - m);
    float se = e;
    #pragma unroll
    for (int d = 32; d; d >>= 1) se += __shfl_xor(se, d);
    out[g * 64 + f] = e / se;
  }
}

extern "C" void kernel_launch(void* const* d_in, const int* in_sizes, int n_in,
                              void* d_out, int out_size, void* d_ws, size_t ws_size,
                              hipStream_t stream) {
  const float* X1    = (const float*)d_in[0];
  const int*   idxup = (const int*)d_in[1];
  const float* valup = (const float*)d_in[2];
  const int*   idxdn = (const int*)d_in[3];
  const float* valdn = (const float*)d_in[4];
  const int*   batch = (const int*)d_in[5];
  const float* W1  = (const float*)d_in[6];
  const float* a11 = (const float*)d_in[7];
  const float* a21 = (const float*)d_in[8];
  const float* W2  = (const float*)d_in[9];
  const float* a12 = (const float*)d_in[10];
  const float* a22 = (const float*)d_in[11];
  const float* W4  = (const float*)d_in[12];
  const float* a14 = (const float*)d_in[13];
  const float* a24 = (const float*)d_in[14];
  float* out = (float*)d_out;

  const int N = N_NODES;
  char* p = (char*)d_ws;
  auto alloc = [&](size_t bytes) { char* q = p; p += (bytes + 255) & ~(size_t)255; return q; };
  int*   rp2  = (int*)alloc((size_t)(N2R + 1) * 4);
  int*   bcnt = (int*)alloc(NB * 4);
  int*   bofs = (int*)alloc((NB + 1) * 4);
  int*   bnxt = (int*)alloc(NB * 4);
  int2*  cv   = (int2*)alloc((size_t)2 * NNZ_CNT * 8);
  float* sbuf = (float*)alloc((size_t)4 * N * 4);
  float* hbuf = (float*)alloc((size_t)N * 64 * 4);   // 51.2 MB; also aliased as tmp during CSR build
  float* Xa   = (float*)alloc((size_t)N * 32 * 4);
  float* X4   = (float*)alloc((size_t)N * 64 * 4);
  int*   goff = (int*)alloc((N_GRAPHS + 1) * 4);
  int2*  tmp  = (int2*)hbuf;   // alias: tmp dead before gemm1 writes hbuf

  // ---- CSR build: bucketed counting sort ----
  hipMemsetAsync(bcnt, 0, NB * 4, stream);
  bucket_count_k<<<(2 * NNZ_CNT + 16383) / 16384, 256, 0, stream>>>(idxup, idxdn, bcnt);
  bucket_scan_k<<<1, 64, 0, stream>>>(bcnt, bofs, bnxt, rp2);
  bucket_scatter_k<<<(2 * NNZ_CNT) / 256, 256, 0, stream>>>(idxup, idxup + NNZ_CNT, valup,
                                                            idxdn, idxdn + NNZ_CNT, valdn, bnxt, tmp);
  bucket_build_k<<<NB, 256, 0, stream>>>(tmp, bofs, rp2, cv);

  // ---- layer 1 ----
  gemm1_k<<<(N + 127) / 128, 256, 0, stream>>>(X1, W1, hbuf, N);
  s_l1_k<<<(N + 255) / 256, 256, 0, stream>>>(hbuf, a11, a21, sbuf, N);
  spmm16_dual_k<<<(2 * N + 3) / 4, 256, 0, stream>>>(rp2, cv, hbuf, sbuf, Xa, N);

  // ---- layer 2 ----
  gemm2_k<<<(N + 255) / 256, 256, 0, stream>>>(Xa, W2, a12, a22, hbuf, sbuf, N);
  spmm16_dual_k<<<(2 * N + 3) / 4, 256, 0, stream>>>(rp2, cv, hbuf, sbuf, Xa, N);

  // ---- layer 4 (heads summed, then relu) ----
  gemm4_k<<<(N + 255) / 256, 256, 0, stream>>>(Xa, W4,        a14,      a24,      hbuf, sbuf, sbuf + N, N);
  spmm64_k<0><<<(N + 3) / 4, 256, 0, stream>>>(rp2,     cv, hbuf, sbuf, sbuf + N, X4, N);
  gemm4_k<<<(N + 255) / 256, 256, 0, stream>>>(Xa, W4 + 2048, a14 + 64, a24 + 64, hbuf, sbuf, sbuf + N, N);
  spmm64_k<1><<<(N + 3) / 4, 256, 0, stream>>>(rp2 + N, cv, hbuf, sbuf, sbuf + N, X4, N);

  // ---- pool + softmax ----
  graph_bounds_k<<<2, 256, 0, stream>>>(batch, N, goff);
  pool_k<<<N_GRAPHS, 256, 0, stream>>>(X4, goff, out);
}

// Round 5
// 1245.952 us; speedup vs baseline: 2.4941x; 2.4941x over previous
//
#include <hip/hip_runtime.h>
#include <hip/hip_bf16.h>
#include <math.h>

#define N_NODES  200000
#define NNZ_CNT  3200000
#define N_GRAPHS 256
#define N2R      400000              // 2*N_NODES concatenated rows (up then down)
#define BSHIFT   9
#define BROWS    512                 // rows per bucket
#define NB       ((N2R + BROWS - 1) / BROWS)   // 782 buckets
#define E_BLK    8192                // entries per scatter block

// ============ CSR build via bucketed counting sort ============
// k1: bucket histogram (LDS-aggregated)
__global__ __launch_bounds__(256) void bucket_count_k(const int* __restrict__ rows0,
                                                      const int* __restrict__ rows1,
                                                      int* __restrict__ bcnt) {
  __shared__ int h[NB];
  int t = threadIdx.x;
  for (int i = t; i < NB; i += 256) h[i] = 0;
  __syncthreads();
  long long base = (long long)blockIdx.x * 16384;
  long long lim = base + 16384; if (lim > 2LL * NNZ_CNT) lim = 2LL * NNZ_CNT;
  for (long long e = base + t; e < lim; e += 256) {
    int r = (e < NNZ_CNT) ? rows0[e] : (rows1[e - NNZ_CNT] + N_NODES);
    atomicAdd(&h[r >> BSHIFT], 1);
  }
  __syncthreads();
  for (int i = t; i < NB; i += 256) if (h[i]) atomicAdd(&bcnt[i], h[i]);
}

// k2: scan 782 bucket counts (one wave), init bofs + bnxt, set rp2[N2R]
__global__ void bucket_scan_k(const int* __restrict__ bcnt, int* __restrict__ bofs,
                              int* __restrict__ bnxt, int* __restrict__ rp2) {
  int t = threadIdx.x;   // 64 threads
  int run = 0;
  for (int base = 0; base < NB; base += 64) {
    int idx = base + t;
    int v = (idx < NB) ? bcnt[idx] : 0;
    int x = v;
    #pragma unroll
    for (int d = 1; d < 64; d <<= 1) { int y = __shfl_up(x, d); if (t >= d) x += y; }
    int excl = run + x - v;
    if (idx < NB) { bofs[idx] = excl; bnxt[idx] = excl; }
    run += __shfl(x, 63);
  }
  if (t == 0) { bofs[NB] = run; rp2[N2R] = run; }
}

// k3: LDS-aggregated scatter — per-block bucket histogram, ONE global atomic
// per (block, touched bucket) to reserve a contiguous range, then LDS-atomic
// sub-placement. ~0.1 global atomics/entry, ~80B contiguous write runs.
__global__ __launch_bounds__(256) void bucket_scatter_k(
    const int* __restrict__ rows0, const int* __restrict__ cols0, const float* __restrict__ vals0,
    const int* __restrict__ rows1, const int* __restrict__ cols1, const float* __restrict__ vals1,
    int* __restrict__ bnxt, int2* __restrict__ tmp) {
  __shared__ int hist[NB];
  __shared__ int base[NB];
  int t = threadIdx.x;
  for (int i = t; i < NB; i += 256) hist[i] = 0;
  __syncthreads();
  long long b0 = (long long)blockIdx.x * E_BLK;
  long long lim = b0 + E_BLK; if (lim > 2LL * NNZ_CNT) lim = 2LL * NNZ_CNT;
  // pass 1: count
  for (long long e = b0 + t; e < lim; e += 256) {
    int r = (e < NNZ_CNT) ? rows0[e] : (rows1[e - NNZ_CNT] + N_NODES);
    atomicAdd(&hist[r >> BSHIFT], 1);
  }
  __syncthreads();
  // reserve ranges
  for (int i = t; i < NB; i += 256) {
    int h = hist[i];
    base[i] = h ? atomicAdd(&bnxt[i], h) : 0;
    hist[i] = 0;
  }
  __syncthreads();
  // pass 2: place
  for (long long e = b0 + t; e < lim; e += 256) {
    int r, c; float v;
    if (e < NNZ_CNT) { r = rows0[e]; c = cols0[e]; v = vals0[e]; }
    else { long long k = e - NNZ_CNT; r = rows1[k] + N_NODES; c = cols1[k]; v = vals1[k]; }
    int bk = r >> BSHIFT;
    int p = base[bk] + atomicAdd(&hist[bk], 1);
    tmp[p] = make_int2(c | ((r & (BROWS - 1)) << 18), __float_as_int(v));
  }
}

// k4: per-bucket CSR finalize — LDS row histogram + scan, coalesced rp2 write,
// then place entries via LDS atomics into the bucket's L2-resident CSR range.
__global__ __launch_bounds__(256) void bucket_build_k(const int2* __restrict__ tmp,
    const int* __restrict__ bofs, int* __restrict__ rp2, int2* __restrict__ cv) {
  __shared__ int hist[BROWS];
  __shared__ int lpos[BROWS];
  int b = blockIdx.x;
  int t = threadIdx.x;
  int beg = bofs[b], end = bofs[b + 1];
  for (int i = t; i < BROWS; i += 256) hist[i] = 0;
  __syncthreads();
  for (int e = beg + t; e < end; e += 256)
    atomicAdd(&hist[(tmp[e].x >> 18) & (BROWS - 1)], 1);
  __syncthreads();
  if (t < 64) {
    int run = beg;
    for (int base = 0; base < BROWS; base += 64) {
      int v = hist[base + t];
      int x = v;
      #pragma unroll
      for (int d = 1; d < 64; d <<= 1) { int y = __shfl_up(x, d); if (t >= d) x += y; }
      lpos[base + t] = run + x - v;
      run += __shfl(x, 63);
    }
  }
  __syncthreads();
  int r0 = b << BSHIFT;
  for (int i = t; i < BROWS; i += 256)
    if (r0 + i < N2R) rp2[r0 + i] = lpos[i];
  __syncthreads();   // rp2 reads of lpos must complete before atomics mutate it
  for (int e = beg + t; e < end; e += 256) {
    int2 ent = tmp[e];
    int rl = (ent.x >> 18) & (BROWS - 1);
    int p = atomicAdd(&lpos[rl], 1);
    cv[p] = make_int2(ent.x & 0x3FFFF, ent.y);
  }
}

// ============ layer-1 GEMM: [N,128] @ [128,32] (heads concat) ============
__global__ __launch_bounds__(256) void gemm1_k(const float* __restrict__ X, const float* __restrict__ W,
                                               float* __restrict__ H, int n) {
  __shared__ float Ws[128 * 32];
  __shared__ float Xs[128 * 33];
  int t = threadIdx.x;
  for (int idx = t; idx < 4096; idx += 256) {
    int hh = idx >> 11, rem = idx & 2047, k = rem >> 4, f = rem & 15;
    Ws[k * 32 + hh * 16 + f] = W[idx];
  }
  int r0 = blockIdx.x * 128;
  int rt = t >> 3, ct = t & 7;
  float acc[4][4];
  #pragma unroll
  for (int i = 0; i < 4; ++i)
    #pragma unroll
    for (int j = 0; j < 4; ++j) acc[i][j] = 0.f;
  for (int k0 = 0; k0 < 128; k0 += 32) {
    __syncthreads();
    #pragma unroll
    for (int pp = 0; pp < 4; ++pp) {
      int f4 = pp * 256 + t;
      int row = f4 >> 3, q = f4 & 7;
      int rr = r0 + row;
      float4 v = make_float4(0.f, 0.f, 0.f, 0.f);
      if (rr < n) v = *(const float4*)&X[rr * 128 + k0 + q * 4];
      Xs[row * 33 + q * 4 + 0] = v.x;
      Xs[row * 33 + q * 4 + 1] = v.y;
      Xs[row * 33 + q * 4 + 2] = v.z;
      Xs[row * 33 + q * 4 + 3] = v.w;
    }
    __syncthreads();
    #pragma unroll
    for (int kk = 0; kk < 32; ++kk) {
      int k = k0 + kk;
      float4 wv = *(const float4*)&Ws[k * 32 + ct * 4];
      float xv[4];
      #pragma unroll
      for (int i = 0; i < 4; ++i) xv[i] = Xs[(rt * 4 + i) * 33 + kk];
      #pragma unroll
      for (int i = 0; i < 4; ++i) {
        acc[i][0] += xv[i] * wv.x;
        acc[i][1] += xv[i] * wv.y;
        acc[i][2] += xv[i] * wv.z;
        acc[i][3] += xv[i] * wv.w;
      }
    }
  }
  #pragma unroll
  for (int i = 0; i < 4; ++i) {
    int rr = r0 + rt * 4 + i;
    if (rr < n)
      *(float4*)&H[rr * 32 + ct * 4] = make_float4(acc[i][0], acc[i][1], acc[i][2], acc[i][3]);
  }
}

// ============ per-row attention scores s1,s2 for layer 1 ============
__global__ void s_l1_k(const float* __restrict__ H, const float* __restrict__ a1,
                       const float* __restrict__ a2, float* __restrict__ s, int n) {
  int i = blockIdx.x * 256 + threadIdx.x;
  if (i >= n) return;
  const float* h = H + (size_t)i * 32;
  float s1u = 0.f, s2u = 0.f, s1d = 0.f, s2d = 0.f;
  #pragma unroll
  for (int f = 0; f < 16; ++f) {
    float au = fabsf(h[f]);
    s1u += au * a1[f]; s2u += au * a2[f];
    float ad = fabsf(h[16 + f]);
    s1d += ad * a1[16 + f]; s2d += ad * a2[16 + f];
  }
  s[i] = s1u; s[n + i] = s2u; s[2 * n + i] = s1d; s[3 * n + i] = s2d;
}

// ============ fused softmax+SpMM, f_out=16, both heads in one launch ============
__global__ __launch_bounds__(256) void spmm16_dual_k(
    const int* __restrict__ rp2, const int2* __restrict__ cv,
    const float* __restrict__ H, const float* __restrict__ s, float* __restrict__ out, int n) {
  int wid2 = (blockIdx.x * 256 + threadIdx.x) >> 6;
  if (wid2 >= 2 * n) return;
  int lane = threadIdx.x & 63;
  int h = (wid2 >= n) ? 1 : 0;
  int wid = wid2 - h * n;
  const float* s1 = s + (size_t)(2 * h) * n;
  const float* s2 = s + (size_t)(2 * h + 1) * n;
  int ho = h * 16;
  int beg = rp2[wid2], end = rp2[wid2 + 1];
  int cnt = end - beg;
  float s1r = s1[wid];
  float4 acc = make_float4(0.f, 0.f, 0.f, 0.f);
  int j = lane >> 2, f = lane & 3;
  if (cnt <= 64) {
    int cl = 0; float vl = 0.f, sc = -1e30f;
    if (lane < cnt) {
      int2 e = cv[beg + lane];
      cl = e.x; vl = __int_as_float(e.y);
      sc = s1r + s2[cl];
    }
    float m = sc;
    #pragma unroll
    for (int d = 32; d; d >>= 1) m = fmaxf(m, __shfl_xor(m, d));
    float el = (lane < cnt) ? __expf(sc - m) : 0.f;
    float es = el;
    #pragma unroll
    for (int d = 32; d; d >>= 1) es += __shfl_xor(es, d);
    float att = (cnt > 0) ? el * vl / es : 0.f;
    for (int t = 0; t < cnt; t += 16) {
      int e = t + j;
      float a = __shfl(att, e);
      int   c = __shfl(cl, e);
      if (e < cnt) {
        const float4 hv = *(const float4*)&H[(size_t)c * 32 + ho + f * 4];
        acc.x += a * hv.x; acc.y += a * hv.y; acc.z += a * hv.z; acc.w += a * hv.w;
      }
    }
  } else {
    float vmax = -1e30f;
    for (int e = beg + lane; e < end; e += 64) vmax = fmaxf(vmax, s1r + s2[cv[e].x]);
    #pragma unroll
    for (int d = 32; d; d >>= 1) vmax = fmaxf(vmax, __shfl_xor(vmax, d));
    float esum = 0.f;
    for (int e = beg + lane; e < end; e += 64) esum += __expf(s1r + s2[cv[e].x] - vmax);
    #pragma unroll
    for (int d = 32; d; d >>= 1) esum += __shfl_xor(esum, d);
    float inv = 1.f / esum;
    for (int t = 0; t < cnt; t += 16) {
      int e = t + j;
      if (e < cnt) {
        int2 ecv = cv[beg + e];
        int c = ecv.x;
        float a = __expf(s1r + s2[c] - vmax) * inv * __int_as_float(ecv.y);
        const float4 hv = *(const float4*)&H[(size_t)c * 32 + ho + f * 4];
        acc.x += a * hv.x; acc.y += a * hv.y; acc.z += a * hv.z; acc.w += a * hv.w;
      }
    }
  }
  #pragma unroll
  for (int d = 4; d < 64; d <<= 1) {
    acc.x += __shfl_xor(acc.x, d);
    acc.y += __shfl_xor(acc.y, d);
    acc.z += __shfl_xor(acc.z, d);
    acc.w += __shfl_xor(acc.w, d);
  }
  if (lane < 4)
    *(float4*)&out[(size_t)wid * 32 + ho + lane * 4] =
      make_float4(fmaxf(acc.x, 0.f), fmaxf(acc.y, 0.f), fmaxf(acc.z, 0.f), fmaxf(acc.w, 0.f));
}

// ============ fused softmax+SpMM, f_out=64 ============
template <int MODE>
__global__ __launch_bounds__(256) void spmm64_k(const int* __restrict__ rp, const int2* __restrict__ cv,
    const float* __restrict__ H, const float* __restrict__ s1,
    const float* __restrict__ s2, float* __restrict__ out, int n) {
  int wid = (blockIdx.x * 256 + threadIdx.x) >> 6;
  if (wid >= n) return;
  int lane = threadIdx.x & 63;
  int beg = rp[wid], end = rp[wid + 1];
  int cnt = end - beg;
  float s1r = s1[wid];
  float4 acc = make_float4(0.f, 0.f, 0.f, 0.f);
  int j = lane >> 4, f = lane & 15;
  if (cnt <= 64) {
    int cl = 0; float vl = 0.f, sc = -1e30f;
    if (lane < cnt) {
      int2 e = cv[beg + lane];
      cl = e.x; vl = __int_as_float(e.y);
      sc = s1r + s2[cl];
    }
    float m = sc;
    #pragma unroll
    for (int d = 32; d; d >>= 1) m = fmaxf(m, __shfl_xor(m, d));
    float el = (lane < cnt) ? __expf(sc - m) : 0.f;
    float es = el;
    #pragma unroll
    for (int d = 32; d; d >>= 1) es += __shfl_xor(es, d);
    float att = (cnt > 0) ? el * vl / es : 0.f;
    for (int t = 0; t < cnt; t += 4) {
      int e = t + j;
      float a = __shfl(att, e);
      int   c = __shfl(cl, e);
      if (e < cnt) {
        const float4 hv = *(const float4*)&H[(size_t)c * 64 + f * 4];
        acc.x += a * hv.x; acc.y += a * hv.y; acc.z += a * hv.z; acc.w += a * hv.w;
      }
    }
  } else {
    float vmax = -1e30f;
    for (int e = beg + lane; e < end; e += 64) vmax = fmaxf(vmax, s1r + s2[cv[e].x]);
    #pragma unroll
    for (int d = 32; d; d >>= 1) vmax = fmaxf(vmax, __shfl_xor(vmax, d));
    float esum = 0.f;
    for (int e = beg + lane; e < end; e += 64) esum += __expf(s1r + s2[cv[e].x] - vmax);
    #pragma unroll
    for (int d = 32; d; d >>= 1) esum += __shfl_xor(esum, d);
    float inv = 1.f / esum;
    for (int t = 0; t < cnt; t += 4) {
      int e = t + j;
      if (e < cnt) {
        int2 ecv = cv[beg + e];
        int c = ecv.x;
        float a = __expf(s1r + s2[c] - vmax) * inv * __int_as_float(ecv.y);
        const float4 hv = *(const float4*)&H[(size_t)c * 64 + f * 4];
        acc.x += a * hv.x; acc.y += a * hv.y; acc.z += a * hv.z; acc.w += a * hv.w;
      }
    }
  }
  #pragma unroll
  for (int d = 16; d < 64; d <<= 1) {
    acc.x += __shfl_xor(acc.x, d);
    acc.y += __shfl_xor(acc.y, d);
    acc.z += __shfl_xor(acc.z, d);
    acc.w += __shfl_xor(acc.w, d);
  }
  if (lane < 16) {
    size_t o = (size_t)wid * 64 + lane * 4;
    if (MODE == 0) {
      *(float4*)&out[o] = acc;
    } else {
      float4 prev = *(const float4*)&out[o];
      *(float4*)&out[o] = make_float4(fmaxf(prev.x + acc.x, 0.f), fmaxf(prev.y + acc.y, 0.f),
                                      fmaxf(prev.z + acc.z, 0.f), fmaxf(prev.w + acc.w, 0.f));
    }
  }
}

// ============ layer-2 GEMM [N,32]@[32,32] + fused s1/s2 ============
__global__ __launch_bounds__(256) void gemm2_k(const float* __restrict__ X, const float* __restrict__ W,
    const float* __restrict__ a1, const float* __restrict__ a2, float* __restrict__ H,
    float* __restrict__ s, int n) {
  __shared__ float Ws[32 * 32];
  int t = threadIdx.x;
  for (int idx = t; idx < 1024; idx += 256) {
    int hh = idx >> 9, rem = idx & 511, k = rem >> 4, f = rem & 15;
    Ws[k * 32 + hh * 16 + f] = W[idx];
  }
  __syncthreads();
  int i = blockIdx.x * 256 + t;
  if (i >= n) return;
  float x[32];
  const float4* xp = (const float4*)(X + (size_t)i * 32);
  #pragma unroll
  for (int q = 0; q < 8; ++q) { float4 v = xp[q]; x[q*4] = v.x; x[q*4+1] = v.y; x[q*4+2] = v.z; x[q*4+3] = v.w; }
  float acc[32];
  #pragma unroll
  for (int c = 0; c < 32; ++c) acc[c] = 0.f;
  #pragma unroll 8
  for (int k = 0; k < 32; ++k) {
    float xk = x[k];
    #pragma unroll
    for (int c = 0; c < 32; ++c) acc[c] += xk * Ws[k * 32 + c];
  }
  float s1u = 0.f, s2u = 0.f, s1d = 0.f, s2d = 0.f;
  #pragma unroll
  for (int f = 0; f < 16; ++f) {
    float au = fabsf(acc[f]);      s1u += au * a1[f];      s2u += au * a2[f];
    float ad = fabsf(acc[16 + f]); s1d += ad * a1[16 + f]; s2d += ad * a2[16 + f];
  }
  float4* hp = (float4*)(H + (size_t)i * 32);
  #pragma unroll
  for (int q = 0; q < 8; ++q) hp[q] = make_float4(acc[q*4], acc[q*4+1], acc[q*4+2], acc[q*4+3]);
  s[i] = s1u; s[n + i] = s2u; s[2 * n + i] = s1d; s[3 * n + i] = s2d;
}

// ============ layer-4 GEMM [N,32]@[32,64] per head + fused s1/s2 ============
__global__ __launch_bounds__(256) void gemm4_k(const float* __restrict__ X, const float* __restrict__ W,
    const float* __restrict__ a1, const float* __restrict__ a2, float* __restrict__ H,
    float* __restrict__ s1o, float* __restrict__ s2o, int n) {
  __shared__ float Ws[32 * 64];
  int t = threadIdx.x;
  for (int idx = t; idx < 2048; idx += 256) Ws[idx] = W[idx];
  __syncthreads();
  int i = blockIdx.x * 256 + t;
  if (i >= n) return;
  float x[32];
  const float4* xp = (const float4*)(X + (size_t)i * 32);
  #pragma unroll
  for (int q = 0; q < 8; ++q) { float4 v = xp[q]; x[q*4] = v.x; x[q*4+1] = v.y; x[q*4+2] = v.z; x[q*4+3] = v.w; }
  float acc[64];
  #pragma unroll
  for (int c = 0; c < 64; ++c) acc[c] = 0.f;
  for (int k = 0; k < 32; ++k) {
    float xk = x[k];
    #pragma unroll
    for (int c = 0; c < 64; ++c) acc[c] += xk * Ws[k * 64 + c];
  }
  float s1v = 0.f, s2v = 0.f;
  #pragma unroll
  for (int c = 0; c < 64; ++c) { float a = fabsf(acc[c]); s1v += a * a1[c]; s2v += a * a2[c]; }
  float4* hp = (float4*)(H + (size_t)i * 64);
  #pragma unroll
  for (int q = 0; q < 16; ++q) hp[q] = make_float4(acc[q*4], acc[q*4+1], acc[q*4+2], acc[q*4+3]);
  s1o[i] = s1v; s2o[i] = s2v;
}

// ============ pooling ============
__global__ void graph_bounds_k(const int* __restrict__ batch, int n, int* __restrict__ off) {
  int g = blockIdx.x * 256 + threadIdx.x;
  if (g > N_GRAPHS) return;
  int lo = 0, hi = n;
  while (lo < hi) { int mid = (lo + hi) >> 1; if (batch[mid] < g) lo = mid + 1; else hi = mid; }
  off[g] = lo;
}

__global__ __launch_bounds__(256) void pool_k(const float* __restrict__ X, const int* __restrict__ off,
                                              float* __restrict__ out) {
  __shared__ float sm[256];
  int g = blockIdx.x;
  int beg = off[g], end = off[g + 1];
  int t = threadIdx.x;
  int f = t & 63, j = t >> 6;
  float acc = 0.f;
  for (int r = beg + j; r < end; r += 4) acc += X[(size_t)r * 64 + f];
  sm[t] = acc;
  __syncthreads();
  if (j == 0) {
    float ssum = sm[f] + sm[64 + f] + sm[128 + f] + sm[192 + f];
    float cnt = (float)(end - beg);
    float p = ssum / fmaxf(cnt, 1.f);
    float m = p;
    #pragma unroll
    for (int d = 32; d; d >>= 1) m = fmaxf(m, __shfl_xor(m, d));
    float e = __expf(p - m);
    float se = e;
    #pragma unroll
    for (int d = 32; d; d >>= 1) se += __shfl_xor(se, d);
    out[g * 64 + f] = e / se;
  }
}

extern "C" void kernel_launch(void* const* d_in, const int* in_sizes, int n_in,
                              void* d_out, int out_size, void* d_ws, size_t ws_size,
                              hipStream_t stream) {
  const float* X1    = (const float*)d_in[0];
  const int*   idxup = (const int*)d_in[1];
  const float* valup = (const float*)d_in[2];
  const int*   idxdn = (const int*)d_in[3];
  const float* valdn = (const float*)d_in[4];
  const int*   batch = (const int*)d_in[5];
  const float* W1  = (const float*)d_in[6];
  const float* a11 = (const float*)d_in[7];
  const float* a21 = (const float*)d_in[8];
  const float* W2  = (const float*)d_in[9];
  const float* a12 = (const float*)d_in[10];
  const float* a22 = (const float*)d_in[11];
  const float* W4  = (const float*)d_in[12];
  const float* a14 = (const float*)d_in[13];
  const float* a24 = (const float*)d_in[14];
  float* out = (float*)d_out;

  const int N = N_NODES;
  char* p = (char*)d_ws;
  auto alloc = [&](size_t bytes) { char* q = p; p += (bytes + 255) & ~(size_t)255; return q; };
  int*   rp2  = (int*)alloc((size_t)(N2R + 1) * 4);
  int*   bcnt = (int*)alloc(NB * 4);
  int*   bofs = (int*)alloc((NB + 1) * 4);
  int*   bnxt = (int*)alloc(NB * 4);
  int2*  cv   = (int2*)alloc((size_t)2 * NNZ_CNT * 8);
  float* sbuf = (float*)alloc((size_t)4 * N * 4);
  float* hbuf = (float*)alloc((size_t)N * 64 * 4);   // 51.2 MB; aliased as tmp during CSR build
  float* Xa   = (float*)alloc((size_t)N * 32 * 4);
  float* X4   = (float*)alloc((size_t)N * 64 * 4);
  int*   goff = (int*)alloc((N_GRAPHS + 1) * 4);
  int2*  tmp  = (int2*)hbuf;   // alias: tmp dead before gemm1 writes hbuf

  // ---- CSR build: bucketed counting sort ----
  hipMemsetAsync(bcnt, 0, NB * 4, stream);
  bucket_count_k<<<(2 * NNZ_CNT + 16383) / 16384, 256, 0, stream>>>(idxup, idxdn, bcnt);
  bucket_scan_k<<<1, 64, 0, stream>>>(bcnt, bofs, bnxt, rp2);
  bucket_scatter_k<<<(2 * NNZ_CNT + E_BLK - 1) / E_BLK, 256, 0, stream>>>(
      idxup, idxup + NNZ_CNT, valup, idxdn, idxdn + NNZ_CNT, valdn, bnxt, tmp);
  bucket_build_k<<<NB, 256, 0, stream>>>(tmp, bofs, rp2, cv);

  // ---- layer 1 ----
  gemm1_k<<<(N + 127) / 128, 256, 0, stream>>>(X1, W1, hbuf, N);
  s_l1_k<<<(N + 255) / 256, 256, 0, stream>>>(hbuf, a11, a21, sbuf, N);
  spmm16_dual_k<<<(2 * N + 3) / 4, 256, 0, stream>>>(rp2, cv, hbuf, sbuf, Xa, N);

  // ---- layer 2 ----
  gemm2_k<<<(N + 255) / 256, 256, 0, stream>>>(Xa, W2, a12, a22, hbuf, sbuf, N);
  spmm16_dual_k<<<(2 * N + 3) / 4, 256, 0, stream>>>(rp2, cv, hbuf, sbuf, Xa, N);

  // ---- layer 4 (heads summed, then relu) ----
  gemm4_k<<<(N + 255) / 256, 256, 0, stream>>>(Xa, W4,        a14,      a24,      hbuf, sbuf, sbuf + N, N);
  spmm64_k<0><<<(N + 3) / 4, 256, 0, stream>>>(rp2,     cv, hbuf, sbuf, sbuf + N, X4, N);
  gemm4_k<<<(N + 255) / 256, 256, 0, stream>>>(Xa, W4 + 2048, a14 + 64, a24 + 64, hbuf, sbuf, sbuf + N, N);
  spmm64_k<1><<<(N + 3) / 4, 256, 0, stream>>>(rp2 + N, cv, hbuf, sbuf, sbuf + N, X4, N);

  // ---- pool + softmax ----
  graph_bounds_k<<<2, 256, 0, stream>>>(batch, N, goff);
  pool_k<<<N_GRAPHS, 256, 0, stream>>>(X4, goff, out);
}

// Round 6
// 1177.173 us; speedup vs baseline: 2.6398x; 1.0584x over previous
//
#include <hip/hip_runtime.h>
#include <hip/hip_bf16.h>
#include <math.h>

#define N_NODES  200000
#define NNZ_CNT  3200000
#define N_GRAPHS 256
#define N2R      400000              // 2*N_NODES concatenated rows (up then down)
#define BSHIFT   9
#define BROWS    512                 // rows per bucket
#define NB       ((N2R + BROWS - 1) / BROWS)   // 782 buckets
#define E_BLK    8192                // entries per scatter block

// ============ CSR build via bucketed counting sort ============
__global__ __launch_bounds__(256) void bucket_count_k(const int* __restrict__ rows0,
                                                      const int* __restrict__ rows1,
                                                      int* __restrict__ bcnt) {
  __shared__ int h[NB];
  int t = threadIdx.x;
  for (int i = t; i < NB; i += 256) h[i] = 0;
  __syncthreads();
  long long base = (long long)blockIdx.x * 16384;
  long long lim = base + 16384; if (lim > 2LL * NNZ_CNT) lim = 2LL * NNZ_CNT;
  for (long long e = base + t; e < lim; e += 256) {
    int r = (e < NNZ_CNT) ? rows0[e] : (rows1[e - NNZ_CNT] + N_NODES);
    atomicAdd(&h[r >> BSHIFT], 1);
  }
  __syncthreads();
  for (int i = t; i < NB; i += 256) if (h[i]) atomicAdd(&bcnt[i], h[i]);
}

__global__ void bucket_scan_k(const int* __restrict__ bcnt, int* __restrict__ bofs,
                              int* __restrict__ bnxt, int* __restrict__ rp2) {
  int t = threadIdx.x;   // 64 threads
  int run = 0;
  for (int base = 0; base < NB; base += 64) {
    int idx = base + t;
    int v = (idx < NB) ? bcnt[idx] : 0;
    int x = v;
    #pragma unroll
    for (int d = 1; d < 64; d <<= 1) { int y = __shfl_up(x, d); if (t >= d) x += y; }
    int excl = run + x - v;
    if (idx < NB) { bofs[idx] = excl; bnxt[idx] = excl; }
    run += __shfl(x, 63);
  }
  if (t == 0) { bofs[NB] = run; rp2[N2R] = run; }
}

__global__ __launch_bounds__(256) void bucket_scatter_k(
    const int* __restrict__ rows0, const int* __restrict__ cols0, const float* __restrict__ vals0,
    const int* __restrict__ rows1, const int* __restrict__ cols1, const float* __restrict__ vals1,
    int* __restrict__ bnxt, int2* __restrict__ tmp) {
  __shared__ int hist[NB];
  __shared__ int base[NB];
  int t = threadIdx.x;
  for (int i = t; i < NB; i += 256) hist[i] = 0;
  __syncthreads();
  long long b0 = (long long)blockIdx.x * E_BLK;
  long long lim = b0 + E_BLK; if (lim > 2LL * NNZ_CNT) lim = 2LL * NNZ_CNT;
  for (long long e = b0 + t; e < lim; e += 256) {
    int r = (e < NNZ_CNT) ? rows0[e] : (rows1[e - NNZ_CNT] + N_NODES);
    atomicAdd(&hist[r >> BSHIFT], 1);
  }
  __syncthreads();
  for (int i = t; i < NB; i += 256) {
    int h = hist[i];
    base[i] = h ? atomicAdd(&bnxt[i], h) : 0;
    hist[i] = 0;
  }
  __syncthreads();
  for (long long e = b0 + t; e < lim; e += 256) {
    int r, c; float v;
    if (e < NNZ_CNT) { r = rows0[e]; c = cols0[e]; v = vals0[e]; }
    else { long long k = e - NNZ_CNT; r = rows1[k] + N_NODES; c = cols1[k]; v = vals1[k]; }
    int bk = r >> BSHIFT;
    int p = base[bk] + atomicAdd(&hist[bk], 1);
    tmp[p] = make_int2(c | ((r & (BROWS - 1)) << 18), __float_as_int(v));
  }
}

__global__ __launch_bounds__(256) void bucket_build_k(const int2* __restrict__ tmp,
    const int* __restrict__ bofs, int* __restrict__ rp2, int2* __restrict__ cv) {
  __shared__ int hist[BROWS];
  __shared__ int lpos[BROWS];
  int b = blockIdx.x;
  int t = threadIdx.x;
  int beg = bofs[b], end = bofs[b + 1];
  for (int i = t; i < BROWS; i += 256) hist[i] = 0;
  __syncthreads();
  for (int e = beg + t; e < end; e += 256)
    atomicAdd(&hist[(tmp[e].x >> 18) & (BROWS - 1)], 1);
  __syncthreads();
  if (t < 64) {
    int run = beg;
    for (int base = 0; base < BROWS; base += 64) {
      int v = hist[base + t];
      int x = v;
      #pragma unroll
      for (int d = 1; d < 64; d <<= 1) { int y = __shfl_up(x, d); if (t >= d) x += y; }
      lpos[base + t] = run + x - v;
      run += __shfl(x, 63);
    }
  }
  __syncthreads();
  int r0 = b << BSHIFT;
  for (int i = t; i < BROWS; i += 256)
    if (r0 + i < N2R) rp2[r0 + i] = lpos[i];
  __syncthreads();
  for (int e = beg + t; e < end; e += 256) {
    int2 ent = tmp[e];
    int rl = (ent.x >> 18) & (BROWS - 1);
    int p = atomicAdd(&lpos[rl], 1);
    cv[p] = make_int2(ent.x & 0x3FFFF, ent.y);
  }
}

// ============ layer-1 GEMM: [N,128] @ [128,32] (heads concat) ============
__global__ __launch_bounds__(256) void gemm1_k(const float* __restrict__ X, const float* __restrict__ W,
                                               float* __restrict__ H, int n) {
  __shared__ float Ws[128 * 32];
  __shared__ float Xs[128 * 33];
  int t = threadIdx.x;
  for (int idx = t; idx < 4096; idx += 256) {
    int hh = idx >> 11, rem = idx & 2047, k = rem >> 4, f = rem & 15;
    Ws[k * 32 + hh * 16 + f] = W[idx];
  }
  int r0 = blockIdx.x * 128;
  int rt = t >> 3, ct = t & 7;
  float acc[4][4];
  #pragma unroll
  for (int i = 0; i < 4; ++i)
    #pragma unroll
    for (int j = 0; j < 4; ++j) acc[i][j] = 0.f;
  for (int k0 = 0; k0 < 128; k0 += 32) {
    __syncthreads();
    #pragma unroll
    for (int pp = 0; pp < 4; ++pp) {
      int f4 = pp * 256 + t;
      int row = f4 >> 3, q = f4 & 7;
      int rr = r0 + row;
      float4 v = make_float4(0.f, 0.f, 0.f, 0.f);
      if (rr < n) v = *(const float4*)&X[rr * 128 + k0 + q * 4];
      Xs[row * 33 + q * 4 + 0] = v.x;
      Xs[row * 33 + q * 4 + 1] = v.y;
      Xs[row * 33 + q * 4 + 2] = v.z;
      Xs[row * 33 + q * 4 + 3] = v.w;
    }
    __syncthreads();
    #pragma unroll
    for (int kk = 0; kk < 32; ++kk) {
      int k = k0 + kk;
      float4 wv = *(const float4*)&Ws[k * 32 + ct * 4];
      float xv[4];
      #pragma unroll
      for (int i = 0; i < 4; ++i) xv[i] = Xs[(rt * 4 + i) * 33 + kk];
      #pragma unroll
      for (int i = 0; i < 4; ++i) {
        acc[i][0] += xv[i] * wv.x;
        acc[i][1] += xv[i] * wv.y;
        acc[i][2] += xv[i] * wv.z;
        acc[i][3] += xv[i] * wv.w;
      }
    }
  }
  #pragma unroll
  for (int i = 0; i < 4; ++i) {
    int rr = r0 + rt * 4 + i;
    if (rr < n)
      *(float4*)&H[rr * 32 + ct * 4] = make_float4(acc[i][0], acc[i][1], acc[i][2], acc[i][3]);
  }
}

// ============ per-row attention scores s1,s2 for layer 1 ============
__global__ void s_l1_k(const float* __restrict__ H, const float* __restrict__ a1,
                       const float* __restrict__ a2, float* __restrict__ s, int n) {
  int i = blockIdx.x * 256 + threadIdx.x;
  if (i >= n) return;
  const float* h = H + (size_t)i * 32;
  float s1u = 0.f, s2u = 0.f, s1d = 0.f, s2d = 0.f;
  #pragma unroll
  for (int f = 0; f < 16; ++f) {
    float au = fabsf(h[f]);
    s1u += au * a1[f]; s2u += au * a2[f];
    float ad = fabsf(h[16 + f]);
    s1d += ad * a1[16 + f]; s2d += ad * a2[16 + f];
  }
  s[i] = s1u; s[n + i] = s2u; s[2 * n + i] = s1d; s[3 * n + i] = s2d;
}

// ============ fused softmax+SpMM, f_out=16, both heads, 2 rows/wave (32 lanes each) ============
__global__ __launch_bounds__(256) void spmm16_dual_k(
    const int* __restrict__ rp2, const int2* __restrict__ cv,
    const float* __restrict__ H, const float* __restrict__ s, float* __restrict__ out, int n) {
  int wave = (blockIdx.x * 256 + threadIdx.x) >> 6;
  int lane = threadIdx.x & 63;
  int half = lane >> 5, sl = lane & 31;
  int wid2 = wave * 2 + half;
  bool active = wid2 < 2 * n;
  int h = (active && wid2 >= n) ? 1 : 0;
  int wid = wid2 - h * n;
  const float* s1 = s + (size_t)(2 * h) * n;
  const float* s2 = s + (size_t)(2 * h + 1) * n;
  int ho = h * 16;
  int beg = 0, end = 0;
  if (active) { beg = rp2[wid2]; end = rp2[wid2 + 1]; }
  int cnt = end - beg;
  float s1r = active ? s1[wid] : 0.f;
  float4 acc = make_float4(0.f, 0.f, 0.f, 0.f);
  int j = sl >> 2, f = sl & 3;   // 8 entry-groups x 4 feature-lanes
  if (cnt <= 32) {
    int cl = 0; float vl = 0.f, sc = -1e30f;
    if (sl < cnt) {
      int2 e = cv[beg + sl];
      cl = e.x; vl = __int_as_float(e.y);
      sc = s1r + s2[cl];
    }
    float m = sc;
    #pragma unroll
    for (int d = 16; d; d >>= 1) m = fmaxf(m, __shfl_xor(m, d));
    float el = (sl < cnt) ? __expf(sc - m) : 0.f;
    float es = el;
    #pragma unroll
    for (int d = 16; d; d >>= 1) es += __shfl_xor(es, d);
    float att = (cnt > 0) ? el * vl / es : 0.f;
    for (int t = 0; t < cnt; t += 8) {
      int e = t + j;
      int srcl = half * 32 + (e & 31);
      float a = __shfl(att, srcl);
      int   c = __shfl(cl, srcl);
      if (e < cnt) {
        const float4 hv = *(const float4*)&H[(size_t)c * 32 + ho + f * 4];
        acc.x += a * hv.x; acc.y += a * hv.y; acc.z += a * hv.z; acc.w += a * hv.w;
      }
    }
  } else {
    float vmax = -1e30f;
    for (int e = beg + sl; e < end; e += 32) vmax = fmaxf(vmax, s1r + s2[cv[e].x]);
    #pragma unroll
    for (int d = 16; d; d >>= 1) vmax = fmaxf(vmax, __shfl_xor(vmax, d));
    float esum = 0.f;
    for (int e = beg + sl; e < end; e += 32) esum += __expf(s1r + s2[cv[e].x] - vmax);
    #pragma unroll
    for (int d = 16; d; d >>= 1) esum += __shfl_xor(esum, d);
    float inv = 1.f / esum;
    for (int t = 0; t < cnt; t += 8) {
      int e = t + j;
      if (e < cnt) {
        int2 ecv = cv[beg + e];
        int c = ecv.x;
        float a = __expf(s1r + s2[c] - vmax) * inv * __int_as_float(ecv.y);
        const float4 hv = *(const float4*)&H[(size_t)c * 32 + ho + f * 4];
        acc.x += a * hv.x; acc.y += a * hv.y; acc.z += a * hv.z; acc.w += a * hv.w;
      }
    }
  }
  #pragma unroll
  for (int d = 4; d < 32; d <<= 1) {
    acc.x += __shfl_xor(acc.x, d);
    acc.y += __shfl_xor(acc.y, d);
    acc.z += __shfl_xor(acc.z, d);
    acc.w += __shfl_xor(acc.w, d);
  }
  if (active && sl < 4)
    *(float4*)&out[(size_t)wid * 32 + ho + sl * 4] =
      make_float4(fmaxf(acc.x, 0.f), fmaxf(acc.y, 0.f), fmaxf(acc.z, 0.f), fmaxf(acc.w, 0.f));
}

// ============ layer-4 fused: softmax+SpMM for BOTH heads, summed + relu, 2 rows/wave ============
__global__ __launch_bounds__(256) void spmm64_dual_k(const int* __restrict__ rp2,
    const int2* __restrict__ cv, const float* __restrict__ H0, const float* __restrict__ H1,
    const float* __restrict__ s, float* __restrict__ out, int n) {
  int wave = (blockIdx.x * 256 + threadIdx.x) >> 6;
  int lane = threadIdx.x & 63;
  int half = lane >> 5, sl = lane & 31;
  int r = wave * 2 + half;
  bool active = r < n;
  int j = sl >> 4, f = sl & 15;   // 2 entry-groups x 16 feature-lanes
  float4 acc = make_float4(0.f, 0.f, 0.f, 0.f);
  #pragma unroll
  for (int hh = 0; hh < 2; ++hh) {
    const float* H  = hh ? H1 : H0;
    const float* s1 = s + (size_t)(2 * hh) * n;
    const float* s2 = s + (size_t)(2 * hh + 1) * n;
    int beg = 0, end = 0;
    if (active) { beg = rp2[hh * n + r]; end = rp2[hh * n + r + 1]; }
    int cnt = end - beg;
    float s1r = active ? s1[r] : 0.f;
    if (cnt <= 32) {
      int cl = 0; float vl = 0.f, sc = -1e30f;
      if (sl < cnt) {
        int2 e = cv[beg + sl];
        cl = e.x; vl = __int_as_float(e.y);
        sc = s1r + s2[cl];
      }
      float m = sc;
      #pragma unroll
      for (int d = 16; d; d >>= 1) m = fmaxf(m, __shfl_xor(m, d));
      float el = (sl < cnt) ? __expf(sc - m) : 0.f;
      float es = el;
      #pragma unroll
      for (int d = 16; d; d >>= 1) es += __shfl_xor(es, d);
      float att = (cnt > 0) ? el * vl / es : 0.f;
      for (int t = 0; t < cnt; t += 2) {
        int e = t + j;
        int srcl = half * 32 + (e & 31);
        float a = __shfl(att, srcl);
        int   c = __shfl(cl, srcl);
        if (e < cnt) {
          const float4 hv = *(const float4*)&H[(size_t)c * 64 + f * 4];
          acc.x += a * hv.x; acc.y += a * hv.y; acc.z += a * hv.z; acc.w += a * hv.w;
        }
      }
    } else {
      float vmax = -1e30f;
      for (int e = beg + sl; e < end; e += 32) vmax = fmaxf(vmax, s1r + s2[cv[e].x]);
      #pragma unroll
      for (int d = 16; d; d >>= 1) vmax = fmaxf(vmax, __shfl_xor(vmax, d));
      float esum = 0.f;
      for (int e = beg + sl; e < end; e += 32) esum += __expf(s1r + s2[cv[e].x] - vmax);
      #pragma unroll
      for (int d = 16; d; d >>= 1) esum += __shfl_xor(esum, d);
      float inv = 1.f / esum;
      for (int t = 0; t < cnt; t += 2) {
        int e = t + j;
        if (e < cnt) {
          int2 ecv = cv[beg + e];
          int c = ecv.x;
          float a = __expf(s1r + s2[c] - vmax) * inv * __int_as_float(ecv.y);
          const float4 hv = *(const float4*)&H[(size_t)c * 64 + f * 4];
          acc.x += a * hv.x; acc.y += a * hv.y; acc.z += a * hv.z; acc.w += a * hv.w;
        }
      }
    }
  }
  acc.x += __shfl_xor(acc.x, 16);
  acc.y += __shfl_xor(acc.y, 16);
  acc.z += __shfl_xor(acc.z, 16);
  acc.w += __shfl_xor(acc.w, 16);
  if (active && sl < 16)
    *(float4*)&out[(size_t)r * 64 + sl * 4] =
      make_float4(fmaxf(acc.x, 0.f), fmaxf(acc.y, 0.f), fmaxf(acc.z, 0.f), fmaxf(acc.w, 0.f));
}

// ============ layer-2 GEMM [N,32]@[32,32] + fused s1/s2 ============
__global__ __launch_bounds__(256) void gemm2_k(const float* __restrict__ X, const float* __restrict__ W,
    const float* __restrict__ a1, const float* __restrict__ a2, float* __restrict__ H,
    float* __restrict__ s, int n) {
  __shared__ float Ws[32 * 32];
  int t = threadIdx.x;
  for (int idx = t; idx < 1024; idx += 256) {
    int hh = idx >> 9, rem = idx & 511, k = rem >> 4, f = rem & 15;
    Ws[k * 32 + hh * 16 + f] = W[idx];
  }
  __syncthreads();
  int i = blockIdx.x * 256 + t;
  if (i >= n) return;
  float x[32];
  const float4* xp = (const float4*)(X + (size_t)i * 32);
  #pragma unroll
  for (int q = 0; q < 8; ++q) { float4 v = xp[q]; x[q*4] = v.x; x[q*4+1] = v.y; x[q*4+2] = v.z; x[q*4+3] = v.w; }
  float acc[32];
  #pragma unroll
  for (int c = 0; c < 32; ++c) acc[c] = 0.f;
  #pragma unroll 8
  for (int k = 0; k < 32; ++k) {
    float xk = x[k];
    #pragma unroll
    for (int c = 0; c < 32; ++c) acc[c] += xk * Ws[k * 32 + c];
  }
  float s1u = 0.f, s2u = 0.f, s1d = 0.f, s2d = 0.f;
  #pragma unroll
  for (int f = 0; f < 16; ++f) {
    float au = fabsf(acc[f]);      s1u += au * a1[f];      s2u += au * a2[f];
    float ad = fabsf(acc[16 + f]); s1d += ad * a1[16 + f]; s2d += ad * a2[16 + f];
  }
  float4* hp = (float4*)(H + (size_t)i * 32);
  #pragma unroll
  for (int q = 0; q < 8; ++q) hp[q] = make_float4(acc[q*4], acc[q*4+1], acc[q*4+2], acc[q*4+3]);
  s[i] = s1u; s[n + i] = s2u; s[2 * n + i] = s1d; s[3 * n + i] = s2d;
}

// ============ layer-4 GEMM [N,32]@[32,64] per head + fused s1/s2 ============
__global__ __launch_bounds__(256) void gemm4_k(const float* __restrict__ X, const float* __restrict__ W,
    const float* __restrict__ a1, const float* __restrict__ a2, float* __restrict__ H,
    float* __restrict__ s1o, float* __restrict__ s2o, int n) {
  __shared__ float Ws[32 * 64];
  int t = threadIdx.x;
  for (int idx = t; idx < 2048; idx += 256) Ws[idx] = W[idx];
  __syncthreads();
  int i = blockIdx.x * 256 + t;
  if (i >= n) return;
  float x[32];
  const float4* xp = (const float4*)(X + (size_t)i * 32);
  #pragma unroll
  for (int q = 0; q < 8; ++q) { float4 v = xp[q]; x[q*4] = v.x; x[q*4+1] = v.y; x[q*4+2] = v.z; x[q*4+3] = v.w; }
  float acc[64];
  #pragma unroll
  for (int c = 0; c < 64; ++c) acc[c] = 0.f;
  for (int k = 0; k < 32; ++k) {
    float xk = x[k];
    #pragma unroll
    for (int c = 0; c < 64; ++c) acc[c] += xk * Ws[k * 64 + c];
  }
  float s1v = 0.f, s2v = 0.f;
  #pragma unroll
  for (int c = 0; c < 64; ++c) { float a = fabsf(acc[c]); s1v += a * a1[c]; s2v += a * a2[c]; }
  float4* hp = (float4*)(H + (size_t)i * 64);
  #pragma unroll
  for (int q = 0; q < 16; ++q) hp[q] = make_float4(acc[q*4], acc[q*4+1], acc[q*4+2], acc[q*4+3]);
  s1o[i] = s1v; s2o[i] = s2v;
}

// ============ pooling ============
__global__ void graph_bounds_k(const int* __restrict__ batch, int n, int* __restrict__ off) {
  int g = blockIdx.x * 256 + threadIdx.x;
  if (g > N_GRAPHS) return;
  int lo = 0, hi = n;
  while (lo < hi) { int mid = (lo + hi) >> 1; if (batch[mid] < g) lo = mid + 1; else hi = mid; }
  off[g] = lo;
}

__global__ __launch_bounds__(256) void pool_k(const float* __restrict__ X, const int* __restrict__ off,
                                              float* __restrict__ out) {
  __shared__ float sm[256];
  int g = blockIdx.x;
  int beg = off[g], end = off[g + 1];
  int t = threadIdx.x;
  int f = t & 63, j = t >> 6;
  float acc = 0.f;
  for (int r = beg + j; r < end; r += 4) acc += X[(size_t)r * 64 + f];
  sm[t] = acc;
  __syncthreads();
  if (j == 0) {
    float ssum = sm[f] + sm[64 + f] + sm[128 + f] + sm[192 + f];
    float cnt = (float)(end - beg);
    float p = ssum / fmaxf(cnt, 1.f);
    float m = p;
    #pragma unroll
    for (int d = 32; d; d >>= 1) m = fmaxf(m, __shfl_xor(m, d));
    float e = __expf(p - m);
    float se = e;
    #pragma unroll
    for (int d = 32; d; d >>= 1) se += __shfl_xor(se, d);
    out[g * 64 + f] = e / se;
  }
}

extern "C" void kernel_launch(void* const* d_in, const int* in_sizes, int n_in,
                              void* d_out, int out_size, void* d_ws, size_t ws_size,
                              hipStream_t stream) {
  const float* X1    = (const float*)d_in[0];
  const int*   idxup = (const int*)d_in[1];
  const float* valup = (const float*)d_in[2];
  const int*   idxdn = (const int*)d_in[3];
  const float* valdn = (const float*)d_in[4];
  const int*   batch = (const int*)d_in[5];
  const float* W1  = (const float*)d_in[6];
  const float* a11 = (const float*)d_in[7];
  const float* a21 = (const float*)d_in[8];
  const float* W2  = (const float*)d_in[9];
  const float* a12 = (const float*)d_in[10];
  const float* a22 = (const float*)d_in[11];
  const float* W4  = (const float*)d_in[12];
  const float* a14 = (const float*)d_in[13];
  const float* a24 = (const float*)d_in[14];
  float* out = (float*)d_out;

  const int N = N_NODES;
  char* p = (char*)d_ws;
  auto alloc = [&](size_t bytes) { char* q = p; p += (bytes + 255) & ~(size_t)255; return q; };
  int*   rp2  = (int*)alloc((size_t)(N2R + 1) * 4);
  int*   bcnt = (int*)alloc(NB * 4);
  int*   bofs = (int*)alloc((NB + 1) * 4);
  int*   bnxt = (int*)alloc(NB * 4);
  int2*  cv   = (int2*)alloc((size_t)2 * NNZ_CNT * 8);
  float* sbuf = (float*)alloc((size_t)4 * N * 4);
  float* hbuf = (float*)alloc((size_t)N * 64 * 4);   // 51.2 MB; aliased as tmp during CSR build
  float* hb2  = (float*)alloc((size_t)N * 64 * 4);   // layer-4 head-1 H
  float* Xa   = (float*)alloc((size_t)N * 32 * 4);
  float* X4   = (float*)alloc((size_t)N * 64 * 4);
  int*   goff = (int*)alloc((N_GRAPHS + 1) * 4);
  int2*  tmp  = (int2*)hbuf;   // alias: tmp dead before gemm1 writes hbuf

  // ---- CSR build: bucketed counting sort ----
  hipMemsetAsync(bcnt, 0, NB * 4, stream);
  bucket_count_k<<<(2 * NNZ_CNT + 16383) / 16384, 256, 0, stream>>>(idxup, idxdn, bcnt);
  bucket_scan_k<<<1, 64, 0, stream>>>(bcnt, bofs, bnxt, rp2);
  bucket_scatter_k<<<(2 * NNZ_CNT + E_BLK - 1) / E_BLK, 256, 0, stream>>>(
      idxup, idxup + NNZ_CNT, valup, idxdn, idxdn + NNZ_CNT, valdn, bnxt, tmp);
  bucket_build_k<<<NB, 256, 0, stream>>>(tmp, bofs, rp2, cv);

  // ---- layer 1 ----
  gemm1_k<<<(N + 127) / 128, 256, 0, stream>>>(X1, W1, hbuf, N);
  s_l1_k<<<(N + 255) / 256, 256, 0, stream>>>(hbuf, a11, a21, sbuf, N);
  spmm16_dual_k<<<(2 * N + 7) / 8, 256, 0, stream>>>(rp2, cv, hbuf, sbuf, Xa, N);

  // ---- layer 2 ----
  gemm2_k<<<(N + 255) / 256, 256, 0, stream>>>(Xa, W2, a12, a22, hbuf, sbuf, N);
  spmm16_dual_k<<<(2 * N + 7) / 8, 256, 0, stream>>>(rp2, cv, hbuf, sbuf, Xa, N);

  // ---- layer 4: both heads' GEMM, then one fused dual-head spmm ----
  gemm4_k<<<(N + 255) / 256, 256, 0, stream>>>(Xa, W4,        a14,      a24,      hbuf, sbuf,         sbuf + N,     N);
  gemm4_k<<<(N + 255) / 256, 256, 0, stream>>>(Xa, W4 + 2048, a14 + 64, a24 + 64, hb2,  sbuf + 2 * N, sbuf + 3 * N, N);
  spmm64_dual_k<<<(N + 7) / 8, 256, 0, stream>>>(rp2, cv, hbuf, hb2, sbuf, X4, N);

  // ---- pool + softmax ----
  graph_bounds_k<<<2, 256, 0, stream>>>(batch, N, goff);
  pool_k<<<N_GRAPHS, 256, 0, stream>>>(X4, goff, out);
}

// Round 7
// 1035.086 us; speedup vs baseline: 3.0022x; 1.1373x over previous
//
#include <hip/hip_runtime.h>
#include <hip/hip_bf16.h>
#include <math.h>

#define N_NODES  200000
#define NNZ_CNT  3200000
#define N_GRAPHS 256
#define N2R      400000              // 2*N_NODES concatenated rows (up then down)
#define BSHIFT   9
#define BROWS    512                 // rows per bucket
#define NB       ((N2R + BROWS - 1) / BROWS)   // 782 buckets
#define E_BLK    8192                // entries per scatter block

// bf16 helpers (RNE pack, shift-unpack)
__device__ __forceinline__ unsigned f2bf(float f) {
  unsigned u = __float_as_uint(f);
  return (u + 0x7fffu + ((u >> 16) & 1u)) >> 16;
}
__device__ __forceinline__ unsigned pack2(float a, float b) { return f2bf(a) | (f2bf(b) << 16); }
__device__ __forceinline__ float bflo(unsigned u) { return __uint_as_float(u << 16); }
__device__ __forceinline__ float bfhi(unsigned u) { return __uint_as_float(u & 0xffff0000u); }

// ============ CSR build via bucketed counting sort ============
__global__ __launch_bounds__(256) void bucket_count_k(const int* __restrict__ rows0,
                                                      const int* __restrict__ rows1,
                                                      int* __restrict__ bcnt) {
  __shared__ int h[NB];
  int t = threadIdx.x;
  for (int i = t; i < NB; i += 256) h[i] = 0;
  __syncthreads();
  long long base = (long long)blockIdx.x * 16384;
  long long lim = base + 16384; if (lim > 2LL * NNZ_CNT) lim = 2LL * NNZ_CNT;
  for (long long e = base + t; e < lim; e += 256) {
    int r = (e < NNZ_CNT) ? rows0[e] : (rows1[e - NNZ_CNT] + N_NODES);
    atomicAdd(&h[r >> BSHIFT], 1);
  }
  __syncthreads();
  for (int i = t; i < NB; i += 256) if (h[i]) atomicAdd(&bcnt[i], h[i]);
}

__global__ void bucket_scan_k(const int* __restrict__ bcnt, int* __restrict__ bofs,
                              int* __restrict__ bnxt, int* __restrict__ rp2) {
  int t = threadIdx.x;   // 64 threads
  int run = 0;
  for (int base = 0; base < NB; base += 64) {
    int idx = base + t;
    int v = (idx < NB) ? bcnt[idx] : 0;
    int x = v;
    #pragma unroll
    for (int d = 1; d < 64; d <<= 1) { int y = __shfl_up(x, d); if (t >= d) x += y; }
    int excl = run + x - v;
    if (idx < NB) { bofs[idx] = excl; bnxt[idx] = excl; }
    run += __shfl(x, 63);
  }
  if (t == 0) { bofs[NB] = run; rp2[N2R] = run; }
}

__global__ __launch_bounds__(256) void bucket_scatter_k(
    const int* __restrict__ rows0, const int* __restrict__ cols0, const float* __restrict__ vals0,
    const int* __restrict__ rows1, const int* __restrict__ cols1, const float* __restrict__ vals1,
    int* __restrict__ bnxt, int2* __restrict__ tmp) {
  __shared__ int hist[NB];
  __shared__ int base[NB];
  int t = threadIdx.x;
  for (int i = t; i < NB; i += 256) hist[i] = 0;
  __syncthreads();
  long long b0 = (long long)blockIdx.x * E_BLK;
  long long lim = b0 + E_BLK; if (lim > 2LL * NNZ_CNT) lim = 2LL * NNZ_CNT;
  for (long long e = b0 + t; e < lim; e += 256) {
    int r = (e < NNZ_CNT) ? rows0[e] : (rows1[e - NNZ_CNT] + N_NODES);
    atomicAdd(&hist[r >> BSHIFT], 1);
  }
  __syncthreads();
  for (int i = t; i < NB; i += 256) {
    int h = hist[i];
    base[i] = h ? atomicAdd(&bnxt[i], h) : 0;
    hist[i] = 0;
  }
  __syncthreads();
  for (long long e = b0 + t; e < lim; e += 256) {
    int r, c; float v;
    if (e < NNZ_CNT) { r = rows0[e]; c = cols0[e]; v = vals0[e]; }
    else { long long k = e - NNZ_CNT; r = rows1[k] + N_NODES; c = cols1[k]; v = vals1[k]; }
    int bk = r >> BSHIFT;
    int p = base[bk] + atomicAdd(&hist[bk], 1);
    tmp[p] = make_int2(c | ((r & (BROWS - 1)) << 18), __float_as_int(v));
  }
}

__global__ __launch_bounds__(256) void bucket_build_k(const int2* __restrict__ tmp,
    const int* __restrict__ bofs, int* __restrict__ rp2, int2* __restrict__ cv) {
  __shared__ int hist[BROWS];
  __shared__ int lpos[BROWS];
  int b = blockIdx.x;
  int t = threadIdx.x;
  int beg = bofs[b], end = bofs[b + 1];
  for (int i = t; i < BROWS; i += 256) hist[i] = 0;
  __syncthreads();
  for (int e = beg + t; e < end; e += 256)
    atomicAdd(&hist[(tmp[e].x >> 18) & (BROWS - 1)], 1);
  __syncthreads();
  if (t < 64) {
    int run = beg;
    for (int base = 0; base < BROWS; base += 64) {
      int v = hist[base + t];
      int x = v;
      #pragma unroll
      for (int d = 1; d < 64; d <<= 1) { int y = __shfl_up(x, d); if (t >= d) x += y; }
      lpos[base + t] = run + x - v;
      run += __shfl(x, 63);
    }
  }
  __syncthreads();
  int r0 = b << BSHIFT;
  for (int i = t; i < BROWS; i += 256)
    if (r0 + i < N2R) rp2[r0 + i] = lpos[i];
  __syncthreads();
  for (int e = beg + t; e < end; e += 256) {
    int2 ent = tmp[e];
    int rl = (ent.x >> 18) & (BROWS - 1);
    int p = atomicAdd(&lpos[rl], 1);
    cv[p] = make_int2(ent.x & 0x3FFFF, ent.y);
  }
}

// ============ layer-1 GEMM: [N,128] @ [128,32] -> bf16 H (heads concat) ============
__global__ __launch_bounds__(256) void gemm1_k(const float* __restrict__ X, const float* __restrict__ W,
                                               unsigned* __restrict__ Hb, int n) {
  __shared__ float Ws[128 * 32];
  __shared__ float Xs[128 * 33];
  int t = threadIdx.x;
  for (int idx = t; idx < 4096; idx += 256) {
    int hh = idx >> 11, rem = idx & 2047, k = rem >> 4, f = rem & 15;
    Ws[k * 32 + hh * 16 + f] = W[idx];
  }
  int r0 = blockIdx.x * 128;
  int rt = t >> 3, ct = t & 7;
  float acc[4][4];
  #pragma unroll
  for (int i = 0; i < 4; ++i)
    #pragma unroll
    for (int j = 0; j < 4; ++j) acc[i][j] = 0.f;
  for (int k0 = 0; k0 < 128; k0 += 32) {
    __syncthreads();
    #pragma unroll
    for (int pp = 0; pp < 4; ++pp) {
      int f4 = pp * 256 + t;
      int row = f4 >> 3, q = f4 & 7;
      int rr = r0 + row;
      float4 v = make_float4(0.f, 0.f, 0.f, 0.f);
      if (rr < n) v = *(const float4*)&X[rr * 128 + k0 + q * 4];
      Xs[row * 33 + q * 4 + 0] = v.x;
      Xs[row * 33 + q * 4 + 1] = v.y;
      Xs[row * 33 + q * 4 + 2] = v.z;
      Xs[row * 33 + q * 4 + 3] = v.w;
    }
    __syncthreads();
    #pragma unroll
    for (int kk = 0; kk < 32; ++kk) {
      int k = k0 + kk;
      float4 wv = *(const float4*)&Ws[k * 32 + ct * 4];
      float xv[4];
      #pragma unroll
      for (int i = 0; i < 4; ++i) xv[i] = Xs[(rt * 4 + i) * 33 + kk];
      #pragma unroll
      for (int i = 0; i < 4; ++i) {
        acc[i][0] += xv[i] * wv.x;
        acc[i][1] += xv[i] * wv.y;
        acc[i][2] += xv[i] * wv.z;
        acc[i][3] += xv[i] * wv.w;
      }
    }
  }
  #pragma unroll
  for (int i = 0; i < 4; ++i) {
    int rr = r0 + rt * 4 + i;
    if (rr < n) {
      uint2 pk = make_uint2(pack2(acc[i][0], acc[i][1]), pack2(acc[i][2], acc[i][3]));
      *(uint2*)&Hb[(size_t)rr * 16 + ct * 2] = pk;
    }
  }
}

// ============ per-row attention scores s1,s2 for layer 1 (bf16 H) ============
__global__ void s_l1_k(const unsigned* __restrict__ Hb, const float* __restrict__ a1,
                       const float* __restrict__ a2, float* __restrict__ s, int n) {
  int i = blockIdx.x * 256 + threadIdx.x;
  if (i >= n) return;
  const unsigned* h = Hb + (size_t)i * 16;
  float s1u = 0.f, s2u = 0.f, s1d = 0.f, s2d = 0.f;
  #pragma unroll
  for (int q = 0; q < 8; ++q) {
    unsigned u0 = h[q];
    float a0 = fabsf(bflo(u0)), b0 = fabsf(bfhi(u0));
    s1u += a0 * a1[2 * q] + b0 * a1[2 * q + 1];
    s2u += a0 * a2[2 * q] + b0 * a2[2 * q + 1];
    unsigned u1 = h[8 + q];
    float a1v = fabsf(bflo(u1)), b1v = fabsf(bfhi(u1));
    s1d += a1v * a1[16 + 2 * q] + b1v * a1[16 + 2 * q + 1];
    s2d += a1v * a2[16 + 2 * q] + b1v * a2[16 + 2 * q + 1];
  }
  s[i] = s1u; s[n + i] = s2u; s[2 * n + i] = s1d; s[3 * n + i] = s2d;
}

// ============ fused softmax+SpMM, f_out=16 bf16 gather, both heads, 2 rows/wave ============
__global__ __launch_bounds__(256) void spmm16_dual_k(
    const int* __restrict__ rp2, const int2* __restrict__ cv,
    const uint2* __restrict__ H, const float* __restrict__ s, float* __restrict__ out, int n) {
  int wave = (blockIdx.x * 256 + threadIdx.x) >> 6;
  int lane = threadIdx.x & 63;
  int half = lane >> 5, sl = lane & 31;
  int wid2 = wave * 2 + half;
  bool active = wid2 < 2 * n;
  int h = (active && wid2 >= n) ? 1 : 0;
  int wid = wid2 - h * n;
  const float* s1 = s + (size_t)(2 * h) * n;
  const float* s2 = s + (size_t)(2 * h + 1) * n;
  int beg = 0, end = 0;
  if (active) { beg = rp2[wid2]; end = rp2[wid2 + 1]; }
  int cnt = end - beg;
  float s1r = active ? s1[wid] : 0.f;
  float4 acc = make_float4(0.f, 0.f, 0.f, 0.f);
  int j = sl >> 2, f = sl & 3;   // 8 entry-groups x 4 feature-lanes (4 bf16 each)
  if (cnt <= 32) {
    int cl = 0; float vl = 0.f, sc = -1e30f;
    if (sl < cnt) {
      int2 e = cv[beg + sl];
      cl = e.x; vl = __int_as_float(e.y);
      sc = s1r + s2[cl];
    }
    float m = sc;
    #pragma unroll
    for (int d = 16; d; d >>= 1) m = fmaxf(m, __shfl_xor(m, d));
    float el = (sl < cnt) ? __expf(sc - m) : 0.f;
    float es = el;
    #pragma unroll
    for (int d = 16; d; d >>= 1) es += __shfl_xor(es, d);
    float att = (cnt > 0) ? el * vl / es : 0.f;
    for (int t = 0; t < cnt; t += 8) {
      int e = t + j;
      int srcl = half * 32 + (e & 31);
      float a = __shfl(att, srcl);
      int   c = __shfl(cl, srcl);
      if (e < cnt) {
        uint2 hv = H[(size_t)c * 8 + h * 4 + f];
        acc.x += a * bflo(hv.x); acc.y += a * bfhi(hv.x);
        acc.z += a * bflo(hv.y); acc.w += a * bfhi(hv.y);
      }
    }
  } else {
    float vmax = -1e30f;
    for (int e = beg + sl; e < end; e += 32) vmax = fmaxf(vmax, s1r + s2[cv[e].x]);
    #pragma unroll
    for (int d = 16; d; d >>= 1) vmax = fmaxf(vmax, __shfl_xor(vmax, d));
    float esum = 0.f;
    for (int e = beg + sl; e < end; e += 32) esum += __expf(s1r + s2[cv[e].x] - vmax);
    #pragma unroll
    for (int d = 16; d; d >>= 1) esum += __shfl_xor(esum, d);
    float inv = 1.f / esum;
    for (int t = 0; t < cnt; t += 8) {
      int e = t + j;
      if (e < cnt) {
        int2 ecv = cv[beg + e];
        int c = ecv.x;
        float a = __expf(s1r + s2[c] - vmax) * inv * __int_as_float(ecv.y);
        uint2 hv = H[(size_t)c * 8 + h * 4 + f];
        acc.x += a * bflo(hv.x); acc.y += a * bfhi(hv.x);
        acc.z += a * bflo(hv.y); acc.w += a * bfhi(hv.y);
      }
    }
  }
  #pragma unroll
  for (int d = 4; d < 32; d <<= 1) {
    acc.x += __shfl_xor(acc.x, d);
    acc.y += __shfl_xor(acc.y, d);
    acc.z += __shfl_xor(acc.z, d);
    acc.w += __shfl_xor(acc.w, d);
  }
  if (active && sl < 4)
    *(float4*)&out[(size_t)wid * 32 + h * 16 + sl * 4] =
      make_float4(fmaxf(acc.x, 0.f), fmaxf(acc.y, 0.f), fmaxf(acc.z, 0.f), fmaxf(acc.w, 0.f));
}

// ============ layer-4 fused: softmax+SpMM both heads bf16 gather, summed+relu, 2 rows/wave ============
__global__ __launch_bounds__(256) void spmm64_dual_k(const int* __restrict__ rp2,
    const int2* __restrict__ cv, const uint2* __restrict__ H0, const uint2* __restrict__ H1,
    const float* __restrict__ s, float* __restrict__ out, int n) {
  int wave = (blockIdx.x * 256 + threadIdx.x) >> 6;
  int lane = threadIdx.x & 63;
  int half = lane >> 5, sl = lane & 31;
  int r = wave * 2 + half;
  bool active = r < n;
  int j = sl >> 4, f = sl & 15;   // 2 entry-groups x 16 feature-lanes (4 bf16 each)
  float4 acc = make_float4(0.f, 0.f, 0.f, 0.f);
  #pragma unroll
  for (int hh = 0; hh < 2; ++hh) {
    const uint2* H  = hh ? H1 : H0;
    const float* s1 = s + (size_t)(2 * hh) * n;
    const float* s2 = s + (size_t)(2 * hh + 1) * n;
    int beg = 0, end = 0;
    if (active) { beg = rp2[hh * n + r]; end = rp2[hh * n + r + 1]; }
    int cnt = end - beg;
    float s1r = active ? s1[r] : 0.f;
    if (cnt <= 32) {
      int cl = 0; float vl = 0.f, sc = -1e30f;
      if (sl < cnt) {
        int2 e = cv[beg + sl];
        cl = e.x; vl = __int_as_float(e.y);
        sc = s1r + s2[cl];
      }
      float m = sc;
      #pragma unroll
      for (int d = 16; d; d >>= 1) m = fmaxf(m, __shfl_xor(m, d));
      float el = (sl < cnt) ? __expf(sc - m) : 0.f;
      float es = el;
      #pragma unroll
      for (int d = 16; d; d >>= 1) es += __shfl_xor(es, d);
      float att = (cnt > 0) ? el * vl / es : 0.f;
      for (int t = 0; t < cnt; t += 2) {
        int e = t + j;
        int srcl = half * 32 + (e & 31);
        float a = __shfl(att, srcl);
        int   c = __shfl(cl, srcl);
        if (e < cnt) {
          uint2 hv = H[(size_t)c * 16 + f];
          acc.x += a * bflo(hv.x); acc.y += a * bfhi(hv.x);
          acc.z += a * bflo(hv.y); acc.w += a * bfhi(hv.y);
        }
      }
    } else {
      float vmax = -1e30f;
      for (int e = beg + sl; e < end; e += 32) vmax = fmaxf(vmax, s1r + s2[cv[e].x]);
      #pragma unroll
      for (int d = 16; d; d >>= 1) vmax = fmaxf(vmax, __shfl_xor(vmax, d));
      float esum = 0.f;
      for (int e = beg + sl; e < end; e += 32) esum += __expf(s1r + s2[cv[e].x] - vmax);
      #pragma unroll
      for (int d = 16; d; d >>= 1) esum += __shfl_xor(esum, d);
      float inv = 1.f / esum;
      for (int t = 0; t < cnt; t += 2) {
        int e = t + j;
        if (e < cnt) {
          int2 ecv = cv[beg + e];
          int c = ecv.x;
          float a = __expf(s1r + s2[c] - vmax) * inv * __int_as_float(ecv.y);
          uint2 hv = H[(size_t)c * 16 + f];
          acc.x += a * bflo(hv.x); acc.y += a * bfhi(hv.x);
          acc.z += a * bflo(hv.y); acc.w += a * bfhi(hv.y);
        }
      }
    }
  }
  acc.x += __shfl_xor(acc.x, 16);
  acc.y += __shfl_xor(acc.y, 16);
  acc.z += __shfl_xor(acc.z, 16);
  acc.w += __shfl_xor(acc.w, 16);
  if (active && sl < 16)
    *(float4*)&out[(size_t)r * 64 + sl * 4] =
      make_float4(fmaxf(acc.x, 0.f), fmaxf(acc.y, 0.f), fmaxf(acc.z, 0.f), fmaxf(acc.w, 0.f));
}

// ============ layer-2 GEMM [N,32]@[32,32] + fused s1/s2 -> bf16 H ============
__global__ __launch_bounds__(256) void gemm2_k(const float* __restrict__ X, const float* __restrict__ W,
    const float* __restrict__ a1, const float* __restrict__ a2, unsigned* __restrict__ Hb,
    float* __restrict__ s, int n) {
  __shared__ float Ws[32 * 32];
  int t = threadIdx.x;
  for (int idx = t; idx < 1024; idx += 256) {
    int hh = idx >> 9, rem = idx & 511, k = rem >> 4, f = rem & 15;
    Ws[k * 32 + hh * 16 + f] = W[idx];
  }
  __syncthreads();
  int i = blockIdx.x * 256 + t;
  if (i >= n) return;
  float x[32];
  const float4* xp = (const float4*)(X + (size_t)i * 32);
  #pragma unroll
  for (int q = 0; q < 8; ++q) { float4 v = xp[q]; x[q*4] = v.x; x[q*4+1] = v.y; x[q*4+2] = v.z; x[q*4+3] = v.w; }
  float acc[32];
  #pragma unroll
  for (int c = 0; c < 32; ++c) acc[c] = 0.f;
  #pragma unroll 8
  for (int k = 0; k < 32; ++k) {
    float xk = x[k];
    #pragma unroll
    for (int c = 0; c < 32; ++c) acc[c] += xk * Ws[k * 32 + c];
  }
  float s1u = 0.f, s2u = 0.f, s1d = 0.f, s2d = 0.f;
  #pragma unroll
  for (int f = 0; f < 16; ++f) {
    float au = fabsf(acc[f]);      s1u += au * a1[f];      s2u += au * a2[f];
    float ad = fabsf(acc[16 + f]); s1d += ad * a1[16 + f]; s2d += ad * a2[16 + f];
  }
  uint4* hp = (uint4*)(Hb + (size_t)i * 16);
  #pragma unroll
  for (int q = 0; q < 4; ++q)
    hp[q] = make_uint4(pack2(acc[8*q], acc[8*q+1]), pack2(acc[8*q+2], acc[8*q+3]),
                       pack2(acc[8*q+4], acc[8*q+5]), pack2(acc[8*q+6], acc[8*q+7]));
  s[i] = s1u; s[n + i] = s2u; s[2 * n + i] = s1d; s[3 * n + i] = s2d;
}

// ============ layer-4 GEMM [N,32]@[32,64] per head + fused s1/s2 -> bf16 H ============
__global__ __launch_bounds__(256) void gemm4_k(const float* __restrict__ X, const float* __restrict__ W,
    const float* __restrict__ a1, const float* __restrict__ a2, unsigned* __restrict__ Hb,
    float* __restrict__ s1o, float* __restrict__ s2o, int n) {
  __shared__ float Ws[32 * 64];
  int t = threadIdx.x;
  for (int idx = t; idx < 2048; idx += 256) Ws[idx] = W[idx];
  __syncthreads();
  int i = blockIdx.x * 256 + t;
  if (i >= n) return;
  float x[32];
  const float4* xp = (const float4*)(X + (size_t)i * 32);
  #pragma unroll
  for (int q = 0; q < 8; ++q) { float4 v = xp[q]; x[q*4] = v.x; x[q*4+1] = v.y; x[q*4+2] = v.z; x[q*4+3] = v.w; }
  float acc[64];
  #pragma unroll
  for (int c = 0; c < 64; ++c) acc[c] = 0.f;
  for (int k = 0; k < 32; ++k) {
    float xk = x[k];
    #pragma unroll
    for (int c = 0; c < 64; ++c) acc[c] += xk * Ws[k * 64 + c];
  }
  float s1v = 0.f, s2v = 0.f;
  #pragma unroll
  for (int c = 0; c < 64; ++c) { float a = fabsf(acc[c]); s1v += a * a1[c]; s2v += a * a2[c]; }
  uint4* hp = (uint4*)(Hb + (size_t)i * 32);
  #pragma unroll
  for (int q = 0; q < 8; ++q)
    hp[q] = make_uint4(pack2(acc[8*q], acc[8*q+1]), pack2(acc[8*q+2], acc[8*q+3]),
                       pack2(acc[8*q+4], acc[8*q+5]), pack2(acc[8*q+6], acc[8*q+7]));
  s1o[i] = s1v; s2o[i] = s2v;
}

// ============ pooling ============
__global__ void graph_bounds_k(const int* __restrict__ batch, int n, int* __restrict__ off) {
  int g = blockIdx.x * 256 + threadIdx.x;
  if (g > N_GRAPHS) return;
  int lo = 0, hi = n;
  while (lo < hi) { int mid = (lo + hi) >> 1; if (batch[mid] < g) lo = mid + 1; else hi = mid; }
  off[g] = lo;
}

__global__ __launch_bounds__(256) void pool_k(const float* __restrict__ X, const int* __restrict__ off,
                                              float* __restrict__ out) {
  __shared__ float sm[256];
  int g = blockIdx.x;
  int beg = off[g], end = off[g + 1];
  int t = threadIdx.x;
  int f = t & 63, j = t >> 6;
  float acc = 0.f;
  for (int r = beg + j; r < end; r += 4) acc += X[(size_t)r * 64 + f];
  sm[t] = acc;
  __syncthreads();
  if (j == 0) {
    float ssum = sm[f] + sm[64 + f] + sm[128 + f] + sm[192 + f];
    float cnt = (float)(end - beg);
    float p = ssum / fmaxf(cnt, 1.f);
    float m = p;
    #pragma unroll
    for (int d = 32; d; d >>= 1) m = fmaxf(m, __shfl_xor(m, d));
    float e = __expf(p - m);
    float se = e;
    #pragma unroll
    for (int d = 32; d; d >>= 1) se += __shfl_xor(se, d);
    out[g * 64 + f] = e / se;
  }
}

extern "C" void kernel_launch(void* const* d_in, const int* in_sizes, int n_in,
                              void* d_out, int out_size, void* d_ws, size_t ws_size,
                              hipStream_t stream) {
  const float* X1    = (const float*)d_in[0];
  const int*   idxup = (const int*)d_in[1];
  const float* valup = (const float*)d_in[2];
  const int*   idxdn = (const int*)d_in[3];
  const float* valdn = (const float*)d_in[4];
  const int*   batch = (const int*)d_in[5];
  const float* W1  = (const float*)d_in[6];
  const float* a11 = (const float*)d_in[7];
  const float* a21 = (const float*)d_in[8];
  const float* W2  = (const float*)d_in[9];
  const float* a12 = (const float*)d_in[10];
  const float* a22 = (const float*)d_in[11];
  const float* W4  = (const float*)d_in[12];
  const float* a14 = (const float*)d_in[13];
  const float* a24 = (const float*)d_in[14];
  float* out = (float*)d_out;

  const int N = N_NODES;
  char* p = (char*)d_ws;
  auto alloc = [&](size_t bytes) { char* q = p; p += (bytes + 255) & ~(size_t)255; return q; };
  int*      rp2  = (int*)alloc((size_t)(N2R + 1) * 4);
  int*      bcnt = (int*)alloc(NB * 4);
  int*      bofs = (int*)alloc((NB + 1) * 4);
  int*      bnxt = (int*)alloc(NB * 4);
  int2*     cv   = (int2*)alloc((size_t)2 * NNZ_CNT * 8);
  float*    sbuf = (float*)alloc((size_t)4 * N * 4);
  unsigned* hb   = (unsigned*)alloc((size_t)N * 16 * 4);   // bf16 H, layers 1/2 (32 bf16/row)
  unsigned* hb4a = (unsigned*)alloc((size_t)N * 32 * 4);   // bf16 H, layer-4 head 0 (64 bf16/row)
  unsigned* hb4b = (unsigned*)alloc((size_t)N * 32 * 4);   // bf16 H, layer-4 head 1
  float*    Xa   = (float*)alloc((size_t)N * 32 * 4);
  float*    X4   = (float*)alloc((size_t)N * 64 * 4);      // 51.2 MB; aliased as tmp during build
  int*      goff = (int*)alloc((N_GRAPHS + 1) * 4);
  int2*     tmp  = (int2*)X4;   // alias: tmp dead before spmm64_dual writes X4

  // ---- CSR build: bucketed counting sort ----
  hipMemsetAsync(bcnt, 0, NB * 4, stream);
  bucket_count_k<<<(2 * NNZ_CNT + 16383) / 16384, 256, 0, stream>>>(idxup, idxdn, bcnt);
  bucket_scan_k<<<1, 64, 0, stream>>>(bcnt, bofs, bnxt, rp2);
  bucket_scatter_k<<<(2 * NNZ_CNT + E_BLK - 1) / E_BLK, 256, 0, stream>>>(
      idxup, idxup + NNZ_CNT, valup, idxdn, idxdn + NNZ_CNT, valdn, bnxt, tmp);
  bucket_build_k<<<NB, 256, 0, stream>>>(tmp, bofs, rp2, cv);

  // ---- layer 1 ----
  gemm1_k<<<(N + 127) / 128, 256, 0, stream>>>(X1, W1, hb, N);
  s_l1_k<<<(N + 255) / 256, 256, 0, stream>>>(hb, a11, a21, sbuf, N);
  spmm16_dual_k<<<(2 * N + 7) / 8, 256, 0, stream>>>(rp2, cv, (const uint2*)hb, sbuf, Xa, N);

  // ---- layer 2 ----
  gemm2_k<<<(N + 255) / 256, 256, 0, stream>>>(Xa, W2, a12, a22, hb, sbuf, N);
  spmm16_dual_k<<<(2 * N + 7) / 8, 256, 0, stream>>>(rp2, cv, (const uint2*)hb, sbuf, Xa, N);

  // ---- layer 4: both heads' GEMM, then one fused dual-head spmm ----
  gemm4_k<<<(N + 255) / 256, 256, 0, stream>>>(Xa, W4,        a14,      a24,      hb4a, sbuf,         sbuf + N,     N);
  gemm4_k<<<(N + 255) / 256, 256, 0, stream>>>(Xa, W4 + 2048, a14 + 64, a24 + 64, hb4b, sbuf + 2 * N, sbuf + 3 * N, N);
  spmm64_dual_k<<<(N + 7) / 8, 256, 0, stream>>>(rp2, cv, (const uint2*)hb4a, (const uint2*)hb4b, sbuf, X4, N);

  // ---- pool + softmax ----
  graph_bounds_k<<<2, 256, 0, stream>>>(batch, N, goff);
  pool_k<<<N_GRAPHS, 256, 0, stream>>>(X4, goff, out);
}